// Round 10
// baseline (2997.017 us; speedup 1.0000x reference)
//
#include <hip/hip_runtime.h>
#include <math.h>

#define SEQ 2049
#define EMB 768
#define NHEADS 12
#define QKVW 2304
#define MROWS 4098
#define MPAD 4224
#define NEGV -1000000000.0f

typedef short bs8 __attribute__((ext_vector_type(8)));
typedef float f4 __attribute__((ext_vector_type(4)));

__device__ __forceinline__ unsigned short f2bf(float f){
  union { float f; unsigned u; } x; x.f = f;
  unsigned r = x.u + 0x7fffu + ((x.u >> 16) & 1u);
  return (unsigned short)(r >> 16);
}
__device__ __forceinline__ unsigned short f2bf_fast(float f){
  union { float f; unsigned u; } x; x.f = f;
  return (unsigned short)((x.u + 0x8000u) >> 16);
}
__device__ __forceinline__ float bf2f(unsigned short u){
  union { unsigned u; float f; } x; x.u = ((unsigned)u) << 16; return x.f;
}

__device__ __forceinline__ float gelu_f(float x){
  float ax = fabsf(x)*0.70710678f;
  float t = 1.f/(1.f + 0.3275911f*ax);
  float p = t*(0.254829592f + t*(-0.284496736f + t*(1.421413741f
            + t*(-1.453152027f + t*1.061405429f))));
  float erfv = 1.f - p*__expf(-ax*ax);
  float s = (x >= 0.f) ? erfv : -erfv;
  return 0.5f*x*(1.f + s);
}

__device__ __forceinline__ void gl_lds16(const void* g, void* l){
  __builtin_amdgcn_global_load_lds((const __attribute__((address_space(1))) void*)g,
                                   (__attribute__((address_space(3))) void*)l, 16, 0, 0);
}

// ---------------- weight transpose fp32 (L,K,N) -> bf16 dst[(l*LD+NOFF+n)*K+k]
__global__ void wtr_k(const float* __restrict__ src, unsigned short* __restrict__ dst,
                      int K, int N, int LD, int NOFF)
{
  __shared__ float tile[32][33];
  int k0 = blockIdx.x*32, n0 = blockIdx.y*32, z = blockIdx.z;
  int tx = threadIdx.x, ty = threadIdx.y;
  const float* s = src + (size_t)z*K*N;
#pragma unroll
  for (int i=0;i<4;++i)
    tile[ty*4+i][tx] = s[(size_t)(k0+ty*4+i)*N + n0+tx];
  __syncthreads();
  unsigned short* dz = dst + ((size_t)z*LD + NOFF)*K;
#pragma unroll
  for (int i=0;i<4;++i)
    dz[(size_t)(n0+ty*4+i)*K + k0+tx] = f2bf(tile[tx][ty*4+i]);
}

__global__ void castconv_k(const float* __restrict__ src, unsigned short* __restrict__ dst){
  size_t i = ((size_t)blockIdx.x*256 + threadIdx.x)*4;
  float4 f = *(const float4*)(src+i);
  dst[i+0]=f2bf(f.x); dst[i+1]=f2bf(f.y); dst[i+2]=f2bf(f.z); dst[i+3]=f2bf(f.w);
}

__global__ void biascat_k(const float* __restrict__ bq, const float* __restrict__ bk,
                          const float* __restrict__ bv, float* __restrict__ dst){
  int i = blockIdx.x*256+threadIdx.x;
  int l = i/QKVW, c = i%QKVW;
  float v = (c<768) ? bq[l*768+c] : (c<1536 ? bk[l*768+c-768] : bv[l*768+c-1536]);
  dst[i] = v;
}

// ---------------- patch extraction
__global__ void patchify_k(const float* __restrict__ x, unsigned short* __restrict__ Xp)
{
  size_t gid = (size_t)blockIdx.x*256 + threadIdx.x;
  size_t oi = gid*4;
  int row = (int)(oi >> 12);
  int c = (int)(oi & 4095);
  int b = row >> 11; int p = row & 2047;
  int pd = p >> 8, ph = (p>>4)&15, pw = p&15;
  int pz = c >> 8, py = (c>>4)&15, px = c&15;
  size_t src = (((size_t)(b*128 + pd*16+pz)*256) + (size_t)(ph*16+py))*256 + (size_t)(pw*16+px);
  float4 f = *(const float4*)(x+src);
  Xp[oi+0]=f2bf(f.x); Xp[oi+1]=f2bf(f.y); Xp[oi+2]=f2bf(f.z); Xp[oi+3]=f2bf(f.w);
}

// ---------------- assemble h = [cls; sum4(P)] + pos, zero pads
__global__ void assemble_k(const float* __restrict__ P, size_t pstride,
                           const float* __restrict__ cls,
                           const float* __restrict__ pos_e, float* __restrict__ H)
{
  int row = blockIdx.x; int t = threadIdx.x;
  float* hr = H + (size_t)row*EMB;
  if (row >= MROWS) { hr[t]=0.f; hr[t+256]=0.f; hr[t+512]=0.f; return; }
  int b = row / SEQ; int pos = row - b*SEQ;
#pragma unroll
  for (int c0=0;c0<3;++c0) {
    int c = t + c0*256;
    float v;
    if (pos==0) v = cls[c];
    else {
      size_t idx = ((size_t)(b*2048 + pos-1))*EMB + c;
      v = P[idx] + P[pstride+idx] + P[2*pstride+idx] + P[3*pstride+idx];
    }
    hr[c] = v + pos_e[(size_t)pos*EMB + c];
  }
}

// ---------------- layernorm row -> bf16
__global__ __launch_bounds__(256) void ln_k(const float* __restrict__ H,
    const float* __restrict__ gam, const float* __restrict__ bet,
    unsigned short* __restrict__ Y)
{
  int row = blockIdx.x, t = threadIdx.x;
  const float* hr = H + (size_t)row*EMB;
  float v0 = hr[t], v1 = hr[t+256], v2 = hr[t+512];
  float s = v0+v1+v2;
#pragma unroll
  for (int off=32; off>=1; off>>=1) s += __shfl_down(s, off);
  __shared__ float r1[4], r2[4];
  if ((t&63)==0) r1[t>>6] = s;
  __syncthreads();
  float mean = (r1[0]+r1[1]+r1[2]+r1[3]) * (1.f/768.f);
  float d0=v0-mean, d1=v1-mean, d2=v2-mean;
  float q = d0*d0+d1*d1+d2*d2;
#pragma unroll
  for (int off=32; off>=1; off>>=1) q += __shfl_down(q, off);
  if ((t&63)==0) r2[t>>6] = q;
  __syncthreads();
  float rstd = rsqrtf((r2[0]+r2[1]+r2[2]+r2[3])*(1.f/768.f) + 1e-5f);
  unsigned short* yr = Y + (size_t)row*EMB;
  yr[t]     = f2bf(d0*rstd*gam[t]     + bet[t]);
  yr[t+256] = f2bf(d1*rstd*gam[t+256] + bet[t+256]);
  yr[t+512] = f2bf(d2*rstd*gam[t+512] + bet[t+512]);
}

// ---------------- fused: H += sum_{s<S} P[s]; Y = LN(H)
template<int S>
__global__ __launch_bounds__(256) void ln_red_k(float* __restrict__ H,
    const float* __restrict__ P, size_t pstride,
    const float* __restrict__ gam, const float* __restrict__ bet,
    unsigned short* __restrict__ Y)
{
  int row = blockIdx.x, t = threadIdx.x;
  size_t base = (size_t)row*EMB;
  float v[3];
#pragma unroll
  for (int c0=0;c0<3;++c0) {
    size_t idx = base + t + c0*256;
    float h = H[idx];
#pragma unroll
    for (int s=0;s<S;++s) h += P[(size_t)s*pstride + idx];
    H[idx] = h; v[c0] = h;
  }
  float s = v[0]+v[1]+v[2];
#pragma unroll
  for (int off=32; off>=1; off>>=1) s += __shfl_down(s, off);
  __shared__ float r1[4], r2[4];
  if ((t&63)==0) r1[t>>6] = s;
  __syncthreads();
  float mean = (r1[0]+r1[1]+r1[2]+r1[3]) * (1.f/768.f);
  float d0=v[0]-mean, d1=v[1]-mean, d2=v[2]-mean;
  float q = d0*d0+d1*d1+d2*d2;
#pragma unroll
  for (int off=32; off>=1; off>>=1) q += __shfl_down(q, off);
  if ((t&63)==0) r2[t>>6] = q;
  __syncthreads();
  float rstd = rsqrtf((r2[0]+r2[1]+r2[2]+r2[3])*(1.f/768.f) + 1e-5f);
  unsigned short* yr = Y + base;
  yr[t]     = f2bf(d0*rstd*gam[t]     + bet[t]);
  yr[t+256] = f2bf(d1*rstd*gam[t+256] + bet[t+256]);
  yr[t+512] = f2bf(d2*rstd*gam[t+512] + bet[t+512]);
}

// ---------------- final layernorm on cls rows -> fp32 out
template<int S>
__global__ __launch_bounds__(256) void final_ln_red_k(const float* __restrict__ H,
   const float* __restrict__ P, size_t pstride,
   const float* __restrict__ gam, const float* __restrict__ bet, float* __restrict__ out)
{
  int b = blockIdx.x, t = threadIdx.x;
  size_t base = (size_t)(b*SEQ)*EMB;
  float v[3];
#pragma unroll
  for (int c0=0;c0<3;++c0) {
    size_t idx = base + t + c0*256;
    float h = H[idx];
#pragma unroll
    for (int s=0;s<S;++s) h += P[(size_t)s*pstride + idx];
    v[c0] = h;
  }
  float s = v[0]+v[1]+v[2];
#pragma unroll
  for (int off=32; off>=1; off>>=1) s += __shfl_down(s, off);
  __shared__ float r1[4], r2[4];
  if ((t&63)==0) r1[t>>6] = s;
  __syncthreads();
  float mean = (r1[0]+r1[1]+r1[2]+r1[3]) * (1.f/768.f);
  float d0=v[0]-mean, d1=v[1]-mean, d2=v[2]-mean;
  float q = d0*d0+d1*d1+d2*d2;
#pragma unroll
  for (int off=32; off>=1; off>>=1) q += __shfl_down(q, off);
  if ((t&63)==0) r2[t>>6] = q;
  __syncthreads();
  float rstd = rsqrtf((r2[0]+r2[1]+r2[2]+r2[3])*(1.f/768.f) + 1e-5f);
  out[b*EMB + t]     = d0*rstd*gam[t]     + bet[t];
  out[b*EMB + t+256] = d1*rstd*gam[t+256] + bet[t+256];
  out[b*EMB + t+512] = d2*rstd*gam[t+512] + bet[t+512];
}

// ---------------- GEMM: 128x128 tile, 3 LDS buffers, depth-2 prefetch (r8 config)
// MODE 0: bf16 out +bias; 1: bf16 out +bias+gelu; 3: f32 split-partial write
template<int MODE, int NSPLIT>
__global__ __launch_bounds__(256) void gemm_k(
    const unsigned short* __restrict__ A,
    const unsigned short* __restrict__ Bt,
    const float* __restrict__ bias,
    unsigned short* __restrict__ Cb,
    float* __restrict__ Cf,
    int K, int ldc, size_t splitStride)
{
  __shared__ __attribute__((aligned(16))) unsigned short lA[3][128*32];
  __shared__ __attribute__((aligned(16))) unsigned short lB[3][128*32];
  const int tid = threadIdx.x;
  const int w = tid>>6, lane = tid&63, g = lane>>4, l16 = lane&15;
  const int lr = lane>>2;
  const int lcs = (((lane&3) ^ ((lane>>3)&3)))*8;
  const int swz = ((g ^ ((l16>>1)&3)))*8;
  const int nwg = gridDim.x*gridDim.y;
  const int id = blockIdx.y*gridDim.x + blockIdx.x;
  const int q = nwg>>3, r = nwg&7, xc = id&7, si = id>>3;
  const int nid = (xc<r ? xc*(q+1) : r*(q+1)+(xc-r)*q) + si;
  const int tm = nid / gridDim.x;
  const int tn = nid - tm*gridDim.x;
  const int kchunk = K / NSPLIT;
  const int kofs = (NSPLIT>1) ? blockIdx.z * kchunk : 0;
  const unsigned short* Ab = A + (size_t)tm*128*K + kofs;
  const unsigned short* Bb = Bt + (size_t)tn*128*K + kofs;
  const int wm = (w>>1)*64, wn = (w&1)*64;
  f4 acc[4][4] = {};
  const int nkt = kchunk>>5;

  auto STAGE = [&](int buf, int kt){
    const size_t ko = (size_t)(kt*32 + lcs);
    gl_lds16(Ab + (size_t)(w*16 + lr)*K + ko,     ((char*)lA[buf]) + w*1024);
    gl_lds16(Ab + (size_t)((w+4)*16 + lr)*K + ko, ((char*)lA[buf]) + (w+4)*1024);
    gl_lds16(Bb + (size_t)(w*16 + lr)*K + ko,     ((char*)lB[buf]) + w*1024);
    gl_lds16(Bb + (size_t)((w+4)*16 + lr)*K + ko, ((char*)lB[buf]) + (w+4)*1024);
  };

  STAGE(0, 0);
  STAGE(1, 1);
  for (int kt=0; kt<nkt; ++kt) {
    const int cur = kt % 3;
    if (kt+2 < nkt) {
      STAGE((kt+2)%3, kt+2);
      asm volatile("s_waitcnt vmcnt(8)" ::: "memory");
    } else if (kt+1 < nkt) {
      asm volatile("s_waitcnt vmcnt(4)" ::: "memory");
    } else {
      asm volatile("s_waitcnt vmcnt(0)" ::: "memory");
    }
    __builtin_amdgcn_sched_barrier(0);
    __builtin_amdgcn_s_barrier();
    bs8 af[4], bf[4];
#pragma unroll
    for (int mi=0;mi<4;++mi) af[mi] = *(const bs8*)(lA[cur] + (wm+mi*16+l16)*32 + swz);
#pragma unroll
    for (int ni=0;ni<4;++ni) bf[ni] = *(const bs8*)(lB[cur] + (wn+ni*16+l16)*32 + swz);
    asm volatile("s_waitcnt lgkmcnt(0)" ::: "memory");
    __builtin_amdgcn_sched_barrier(0);
    __builtin_amdgcn_s_barrier();
#pragma unroll
    for (int mi=0;mi<4;++mi)
#pragma unroll
      for (int ni=0;ni<4;++ni)
        acc[mi][ni] = __builtin_amdgcn_mfma_f32_16x16x32_bf16(af[mi], bf[ni], acc[mi][ni], 0,0,0);
  }
  const float bscale = (NSPLIT==1 || blockIdx.z==0) ? 1.f : 0.f;
#pragma unroll
  for (int mi=0;mi<4;++mi)
#pragma unroll
    for (int ni=0;ni<4;++ni) {
      int col = tn*128 + wn + ni*16 + l16;
      float bv = bias[col]*bscale;
#pragma unroll
      for (int r0=0;r0<4;++r0) {
        int row = tm*128 + wm + mi*16 + g*4 + r0;
        float val = acc[mi][ni][r0] + bv;
        if (MODE==1) val = gelu_f(val);
        if (MODE<=1) Cb[(size_t)row*ldc + col] = f2bf(val);
        else Cf[(size_t)blockIdx.z*splitStride + (size_t)row*ldc + col] = val;
      }
    }
}

// ---------------- fused dilated attention: Pl aliased onto lK (LDS 53->35.8 KB,
// 4 blocks/CU); extra barrier after QK^T protects the alias.
__global__ __launch_bounds__(256, 4) void attn_all_k(
    const unsigned short* __restrict__ qkv,
    unsigned short* __restrict__ O1, float* __restrict__ L1,
    unsigned short* __restrict__ O2, float* __restrict__ L2,
    unsigned short* __restrict__ O3, float* __restrict__ L3)
{
  // lK: 128*72 shorts (18.4KB); lVt: 64*136 shorts (17.4KB); Pl aliases lK
  __shared__ __attribute__((aligned(16))) unsigned short lsm[128*72 + 64*136];
  unsigned short* lK  = lsm;
  unsigned short* lVt = lsm + 128*72;
  const int tid = threadIdx.x;
  const int w = tid>>6, lane = tid&63, g = lane>>4, l16 = lane&15;

  int id = (blockIdx.x & 7)*240 + (blockIdx.x >> 3);
  int R, WSZ, NSEG; unsigned short* OB; float* LB;
  if (id < 960)       { R=1; WSZ=512;  NSEG=5; OB=O1; LB=L1; }
  else if (id < 1536) { id -= 960;  R=2; WSZ=1024; NSEG=3; OB=O2; LB=L2; }
  else                { id -= 1536; R=4; WSZ=2048; NSEG=2; OB=O3; LB=L3; }
  const int qt = id & 7; int rest = id >> 3;
  const int seg = rest % NSEG; const int bh = rest / NSEG;
  const int b = bh / NHEADS, hd = bh % NHEADS;
  const int hr = hd % R;
  const int kbase = seg*WSZ + hr;
  bs8 z = {0,0,0,0,0,0,0,0};

  if (kbase + qt*64*R >= SEQ) {
    size_t ob2 = ((size_t)(b*NSEG + seg)*NHEADS + hd)*512 + qt*64;
    int row = tid>>2, cb = (tid&3)*16;
    *(bs8*)(&OB[(ob2 + row)*64 + cb])     = z;
    *(bs8*)(&OB[(ob2 + row)*64 + cb + 8]) = z;
    if (tid < 64) LB[ob2 + tid] = NEGV;
    return;
  }
  int nvk = (SEQ - 1 - kbase)/R + 1; if (nvk > 512) nvk = 512;
  const int nck = (nvk + 127) >> 7;

  const int j0 = qt*64 + w*16;
  const unsigned short* qkvb = qkv + (size_t)b*SEQ*QKVW;

  bs8 qf0 = z, qf1 = z;
  {
    int qpos = kbase + (j0 + l16)*R;
    if (qpos < SEQ) {
      const unsigned short* qrow = qkvb + (size_t)qpos*QKVW + hd*64 + g*8;
      qf0 = *(const bs8*)(qrow);
      qf1 = *(const bs8*)(qrow + 32);
    }
  }

  const int dbK = tid&7, kkKb = tid>>3;
  const int kkV = tid&127, dbV0 = tid>>7;
  const unsigned short* pK = qkvb + (size_t)(kbase + kkKb*R)*QKVW + EMB + hd*64 + dbK*8;
  const unsigned short* pV = qkvb + (size_t)(kbase + kkV*R)*QKVW + 1536 + hd*64 + dbV0*8;
  const size_t stepIt = (size_t)32*R*QKVW;
  const size_t stepC  = (size_t)128*R*QKVW;
  int ci = 0;
  bs8 kreg[4], vreg[4];
  auto ISSUE = [&](){
    const bool full = (kbase + (ci*128 + 127)*R) < SEQ;
    if (full) {
#pragma unroll
      for (int it=0; it<4; ++it) kreg[it] = *(const bs8*)(pK + (size_t)it*stepIt);
#pragma unroll
      for (int it=0; it<4; ++it) vreg[it] = *(const bs8*)(pV + it*16);
    } else {
      const int cofs = ci*128*R;
#pragma unroll
      for (int it=0; it<4; ++it)
        kreg[it] = (kbase + (kkKb + it*32)*R + cofs < SEQ)
                   ? *(const bs8*)(pK + (size_t)it*stepIt) : z;
      const bool vv = (kbase + kkV*R + cofs) < SEQ;
#pragma unroll
      for (int it=0; it<4; ++it) vreg[it] = vv ? *(const bs8*)(pV + it*16) : z;
    }
    pK += stepC; pV += stepC; ++ci;
  };

  float rm[4], rs[4];
  f4 oacc[4] = {};
#pragma unroll
  for (int r=0;r<4;++r) { rm[r] = NEGV; rs[r] = 0.f; }

  ISSUE();
  for (int c=0; c<nck; ++c) {
    __syncthreads();                // all waves done with PV(c-1): lK(Pl) & lVt free
#pragma unroll
    for (int it=0; it<4; ++it) {
      *(bs8*)(lK + (kkKb + it*32)*72 + dbK*8) = kreg[it];
#pragma unroll
      for (int ii=0; ii<8; ++ii) lVt[((dbV0+it*2)*8+ii)*136 + kkV] = (unsigned short)vreg[it][ii];
    }
    __syncthreads();                // chunk c staged, visible
    if (c+1 < nck) ISSUE();         // next chunk's loads overlap compute

    const bool fullc = (kbase + (c*128 + 127)*R) < SEQ;
    f4 sc[8];
    __builtin_amdgcn_s_setprio(1);
#pragma unroll
    for (int kt=0; kt<8; ++kt) {
      int key = kt*16 + l16;
      bs8 kf0 = *(const bs8*)(lK + key*72 + g*8);
      bs8 kf1 = *(const bs8*)(lK + key*72 + 32 + g*8);
      f4 acc = {0.f,0.f,0.f,0.f};
      acc = __builtin_amdgcn_mfma_f32_16x16x32_bf16(qf0, kf0, acc, 0,0,0);
      acc = __builtin_amdgcn_mfma_f32_16x16x32_bf16(qf1, kf1, acc, 0,0,0);
      sc[kt] = acc;
    }
    __builtin_amdgcn_s_setprio(0);
    __syncthreads();                // all waves done reading lK -> Pl may overwrite it
    if (fullc) {
#pragma unroll
      for (int kt=0; kt<8; ++kt)
#pragma unroll
        for (int r=0;r<4;++r) sc[kt][r] *= 0.125f;
    } else {
#pragma unroll
      for (int kt=0; kt<8; ++kt) {
        bool kvld = (kbase + (c*128 + kt*16 + l16)*R) < SEQ;
#pragma unroll
        for (int r=0;r<4;++r) sc[kt][r] = kvld ? sc[kt][r]*0.125f : NEGV;
      }
    }
    float scl[4];
#pragma unroll
    for (int r=0;r<4;++r) {
      float mx = sc[0][r];
#pragma unroll
      for (int kt=1;kt<8;++kt) mx = fmaxf(mx, sc[kt][r]);
      mx = fmaxf(mx, __shfl_xor(mx, 1));
      mx = fmaxf(mx, __shfl_xor(mx, 2));
      mx = fmaxf(mx, __shfl_xor(mx, 4));
      mx = fmaxf(mx, __shfl_xor(mx, 8));
      float mn = fmaxf(rm[r], mx);
      scl[r] = __expf(rm[r] - mn);
      rm[r] = mn;
    }
#pragma unroll
    for (int r=0;r<4;++r) {
      float sm = 0.f;
#pragma unroll
      for (int kt=0;kt<8;++kt) { float p = __expf(sc[kt][r] - rm[r]); sc[kt][r] = p; sm += p; }
      rs[r] = rs[r]*scl[r] + sm;
    }
    if (scl[0]<1.f || scl[1]<1.f || scl[2]<1.f || scl[3]<1.f) {
#pragma unroll
      for (int dt=0; dt<4; ++dt)
#pragma unroll
        for (int r=0;r<4;++r) oacc[dt][r] *= scl[r];
    }
    // Pl aliases lK: per-wave region [w*16..w*16+15] rows of stride 136
    unsigned short* Plw = lK + w*16*136;
#pragma unroll
    for (int kt=0;kt<8;++kt)
#pragma unroll
      for (int r=0;r<4;++r)
        Plw[(g*4+r)*136 + kt*16+l16] = f2bf_fast(sc[kt][r]);
    __builtin_amdgcn_s_setprio(1);
#pragma unroll
    for (int ks=0; ks<4; ++ks) {
      bs8 pa = *(const bs8*)(Plw + l16*136 + ks*32 + g*8);
#pragma unroll
      for (int dt=0; dt<4; ++dt) {
        bs8 vb = *(const bs8*)(lVt + (dt*16+l16)*136 + ks*32 + g*8);
        oacc[dt] = __builtin_amdgcn_mfma_f32_16x16x32_bf16(pa, vb, oacc[dt], 0,0,0);
      }
    }
    __builtin_amdgcn_s_setprio(0);
  }

#pragma unroll
  for (int r=0;r<4;++r) {
    float s = rs[r];
    s += __shfl_xor(s, 1); s += __shfl_xor(s, 2);
    s += __shfl_xor(s, 4); s += __shfl_xor(s, 8);
    rs[r] = s;
  }

  size_t obase = ((size_t)(b*NSEG + seg)*NHEADS + hd)*512;
#pragma unroll
  for (int dt=0; dt<4; ++dt)
#pragma unroll
    for (int r=0;r<4;++r) {
      int j = j0 + g*4 + r;
      OB[(obase + j)*64 + dt*16 + l16] = f2bf(oacc[dt][r] / rs[r]);
    }
  if (l16 == 0) {
#pragma unroll
    for (int r=0;r<4;++r) LB[obase + j0 + g*4 + r] = rm[r] + __logf(rs[r]);
  }
}

// ---------------- combine 3 branches via lse softmax -> attn bf16 (MPAD,768)
__global__ __launch_bounds__(256) void attn_combine_k(
   const unsigned short* __restrict__ o1, const float* __restrict__ l1,
   const unsigned short* __restrict__ o2, const float* __restrict__ l2,
   const unsigned short* __restrict__ o3, const float* __restrict__ l3,
   unsigned short* __restrict__ attn)
{
  int row = blockIdx.x; int t = threadIdx.x;
  unsigned short* arow = attn + (size_t)row*EMB;
  if (row >= MROWS) { arow[t]=0; arow[t+256]=0; arow[t+512]=0; return; }
  int b = row / SEQ, pos = row - (row/SEQ)*SEQ;
#pragma unroll
  for (int c0=0; c0<3; ++c0) {
    int cc = t + c0*256;
    int hd = cc >> 6, d = cc & 63;
    float L0,L1v,L2v,O0,O1v,O2v;
    {
      int seg = pos >> 9; int j = pos & 511;
      size_t base = ((size_t)(b*5 + seg)*NHEADS + hd)*512 + j;
      L0 = l1[base]; O0 = bf2f(o1[base*64 + d]);
    }
    if ((pos & 1) == (hd & 1)) {
      int seg = pos >> 10; int j = ((pos & 1023) - (hd&1)) >> 1;
      size_t base = ((size_t)(b*3 + seg)*NHEADS + hd)*512 + j;
      L1v = l2[base]; O1v = bf2f(o2[base*64 + d]);
    } else { L1v = NEGV; O1v = 0.f; }
    if ((pos & 3) == (hd & 3)) {
      int seg = pos >> 11; int j = ((pos & 2047) - (hd&3)) >> 2;
      size_t base = ((size_t)(b*2 + seg)*NHEADS + hd)*512 + j;
      L2v = l3[base]; O2v = bf2f(o3[base*64 + d]);
    } else { L2v = NEGV; O2v = 0.f; }
    float m = fmaxf(L0, fmaxf(L1v, L2v));
    float e0 = __expf(L0-m), e1 = __expf(L1v-m), e2 = __expf(L2v-m);
    float inv = 1.f/(e0+e1+e2);
    arow[cc] = f2bf((e0*O0+e1*O1v+e2*O2v)*inv);
  }
}

extern "C" void kernel_launch(void* const* d_in, const int* in_sizes, int n_in,
                              void* d_out, int out_size, void* d_ws, size_t ws_size,
                              hipStream_t stream) {
  const float* x       = (const float*)d_in[0];
  const float* conv_w  = (const float*)d_in[1];
  const float* conv_b  = (const float*)d_in[2];
  const float* cls     = (const float*)d_in[3];
  const float* pos_e   = (const float*)d_in[4];
  const float* ln1_g   = (const float*)d_in[5];
  const float* ln1_b   = (const float*)d_in[6];
  const float* wq      = (const float*)d_in[7];
  const float* bq      = (const float*)d_in[8];
  const float* wk      = (const float*)d_in[9];
  const float* bk      = (const float*)d_in[10];
  const float* wv      = (const float*)d_in[11];
  const float* bv      = (const float*)d_in[12];
  const float* wo      = (const float*)d_in[13];
  const float* bo      = (const float*)d_in[14];
  const float* ln2_g   = (const float*)d_in[15];
  const float* ln2_b   = (const float*)d_in[16];
  const float* w1      = (const float*)d_in[17];
  const float* b1      = (const float*)d_in[18];
  const float* w2      = (const float*)d_in[19];
  const float* b2      = (const float*)d_in[20];
  const float* nf_g    = (const float*)d_in[21];
  const float* nf_b    = (const float*)d_in[22];

  char* ws = (char*)d_ws;
  size_t off = 0;
  auto alloc = [&](size_t bytes)->char* {
    char* p = ws + off; off += (bytes + 255) & ~(size_t)255; return p;
  };
  unsigned short* wqkv_t = (unsigned short*)alloc((size_t)12*2304*768*2);
  unsigned short* wo_t   = (unsigned short*)alloc((size_t)12*768*768*2);
  unsigned short* w1_t   = (unsigned short*)alloc((size_t)12*3072*768*2);
  unsigned short* w2_t   = (unsigned short*)alloc((size_t)12*768*3072*2);
  unsigned short* cw_b   = (unsigned short*)alloc((size_t)768*4096*2);
  float* bqkv            = (float*)alloc((size_t)12*2304*4);
  unsigned short* Xp     = (unsigned short*)alloc((size_t)4096*4096*2);
  float* H               = (float*)alloc((size_t)MPAD*768*4);
  float* P               = (float*)alloc((size_t)4*MPAD*768*4);
  unsigned short* Y      = (unsigned short*)alloc((size_t)MPAD*768*2);
  unsigned short* QKV    = (unsigned short*)alloc((size_t)MPAD*2304*2);
  unsigned short* ATT    = (unsigned short*)alloc((size_t)MPAD*768*2);
  unsigned short* Y2     = (unsigned short*)alloc((size_t)MPAD*3072*2);
  unsigned short* O1 = (unsigned short*)alloc((size_t)2*5*12*512*64*2);
  unsigned short* O2 = (unsigned short*)alloc((size_t)2*3*12*512*64*2);
  unsigned short* O3 = (unsigned short*)alloc((size_t)2*2*12*512*64*2);
  float* L1 = (float*)alloc((size_t)2*5*12*512*4);
  float* L2 = (float*)alloc((size_t)2*3*12*512*4);
  float* L3 = (float*)alloc((size_t)2*2*12*512*4);
  const size_t PSTR = (size_t)MPAD*768;

  dim3 tb(32,8);
  wtr_k<<<dim3(24,24,12), tb, 0, stream>>>(wq, wqkv_t, 768, 768, 2304, 0);
  wtr_k<<<dim3(24,24,12), tb, 0, stream>>>(wk, wqkv_t, 768, 768, 2304, 768);
  wtr_k<<<dim3(24,24,12), tb, 0, stream>>>(wv, wqkv_t, 768, 768, 2304, 1536);
  wtr_k<<<dim3(24,24,12), tb, 0, stream>>>(wo, wo_t, 768, 768, 768, 0);
  wtr_k<<<dim3(24,96,12), tb, 0, stream>>>(w1, w1_t, 768, 3072, 3072, 0);
  wtr_k<<<dim3(96,24,12), tb, 0, stream>>>(w2, w2_t, 3072, 768, 768, 0);
  castconv_k<<<3072,256,0,stream>>>(conv_w, cw_b);
  biascat_k<<<108,256,0,stream>>>(bq,bk,bv,bqkv);
  patchify_k<<<16384,256,0,stream>>>(x, Xp);
  gemm_k<3,4><<<dim3(6,32,4),256,0,stream>>>(Xp, cw_b, conv_b, nullptr, P, 4096, 768, PSTR);
  assemble_k<<<MPAD,256,0,stream>>>(P, PSTR, cls, pos_e, H);

  for (int l=0;l<12;++l) {
    if (l==0) ln_k<<<MPAD,256,0,stream>>>(H, ln1_g, ln1_b, Y);
    else ln_red_k<2><<<MPAD,256,0,stream>>>(H, P, PSTR, ln1_g + l*768, ln1_b + l*768, Y);
    gemm_k<0,1><<<dim3(18,33),256,0,stream>>>(Y, wqkv_t + (size_t)l*2304*768, bqkv + l*2304, QKV, nullptr, 768, 2304, 0);
    attn_all_k<<<1920,256,0,stream>>>(QKV, O1,L1,O2,L2,O3,L3);
    attn_combine_k<<<MPAD,256,0,stream>>>(O1,L1,O2,L2,O3,L3, ATT);
    gemm_k<3,2><<<dim3(6,33,2),256,0,stream>>>(ATT, wo_t + (size_t)l*768*768, bo + l*768, nullptr, P, 768, 768, PSTR);
    ln_red_k<2><<<MPAD,256,0,stream>>>(H, P, PSTR, ln2_g + l*768, ln2_b + l*768, Y);
    gemm_k<1,1><<<dim3(24,33),256,0,stream>>>(Y, w1_t + (size_t)l*3072*768, b1 + l*3072, Y2, nullptr, 768, 3072, 0);
    gemm_k<3,2><<<dim3(6,33,2),256,0,stream>>>(Y2, w2_t + (size_t)l*768*3072, b2 + l*768, nullptr, P, 3072, 768, PSTR);
  }
  final_ln_red_k<2><<<2,256,0,stream>>>(H, P, PSTR, nf_g, nf_b, (float*)d_out);
}

// Round 11
// 2747.918 us; speedup vs baseline: 1.0907x; 1.0907x over previous
//
#include <hip/hip_runtime.h>
#include <math.h>

#define SEQ 2049
#define EMB 768
#define NHEADS 12
#define QKVW 2304
#define MROWS 4098
#define MPAD 4224
#define NEGV -1000000000.0f

typedef short bs8 __attribute__((ext_vector_type(8)));
typedef float f4 __attribute__((ext_vector_type(4)));

__device__ __forceinline__ unsigned short f2bf(float f){
  union { float f; unsigned u; } x; x.f = f;
  unsigned r = x.u + 0x7fffu + ((x.u >> 16) & 1u);
  return (unsigned short)(r >> 16);
}
__device__ __forceinline__ unsigned short f2bf_fast(float f){
  union { float f; unsigned u; } x; x.f = f;
  return (unsigned short)((x.u + 0x8000u) >> 16);
}
__device__ __forceinline__ float bf2f(unsigned short u){
  union { unsigned u; float f; } x; x.u = ((unsigned)u) << 16; return x.f;
}

__device__ __forceinline__ float gelu_f(float x){
  float ax = fabsf(x)*0.70710678f;
  float t = 1.f/(1.f + 0.3275911f*ax);
  float p = t*(0.254829592f + t*(-0.284496736f + t*(1.421413741f
            + t*(-1.453152027f + t*1.061405429f))));
  float erfv = 1.f - p*__expf(-ax*ax);
  float s = (x >= 0.f) ? erfv : -erfv;
  return 0.5f*x*(1.f + s);
}

__device__ __forceinline__ void gl_lds16(const void* g, void* l){
  __builtin_amdgcn_global_load_lds((const __attribute__((address_space(1))) void*)g,
                                   (__attribute__((address_space(3))) void*)l, 16, 0, 0);
}

// ---------------- weight transpose fp32 (L,K,N) -> bf16 dst[(l*LD+NOFF+n)*K+k]
__global__ void wtr_k(const float* __restrict__ src, unsigned short* __restrict__ dst,
                      int K, int N, int LD, int NOFF)
{
  __shared__ float tile[32][33];
  int k0 = blockIdx.x*32, n0 = blockIdx.y*32, z = blockIdx.z;
  int tx = threadIdx.x, ty = threadIdx.y;
  const float* s = src + (size_t)z*K*N;
#pragma unroll
  for (int i=0;i<4;++i)
    tile[ty*4+i][tx] = s[(size_t)(k0+ty*4+i)*N + n0+tx];
  __syncthreads();
  unsigned short* dz = dst + ((size_t)z*LD + NOFF)*K;
#pragma unroll
  for (int i=0;i<4;++i)
    dz[(size_t)(n0+ty*4+i)*K + k0+tx] = f2bf(tile[tx][ty*4+i]);
}

__global__ void castconv_k(const float* __restrict__ src, unsigned short* __restrict__ dst){
  size_t i = ((size_t)blockIdx.x*256 + threadIdx.x)*4;
  float4 f = *(const float4*)(src+i);
  dst[i+0]=f2bf(f.x); dst[i+1]=f2bf(f.y); dst[i+2]=f2bf(f.z); dst[i+3]=f2bf(f.w);
}

__global__ void biascat_k(const float* __restrict__ bq, const float* __restrict__ bk,
                          const float* __restrict__ bv, float* __restrict__ dst){
  int i = blockIdx.x*256+threadIdx.x;
  int l = i/QKVW, c = i%QKVW;
  float v = (c<768) ? bq[l*768+c] : (c<1536 ? bk[l*768+c-768] : bv[l*768+c-1536]);
  dst[i] = v;
}

// ---------------- patch extraction
__global__ void patchify_k(const float* __restrict__ x, unsigned short* __restrict__ Xp)
{
  size_t gid = (size_t)blockIdx.x*256 + threadIdx.x;
  size_t oi = gid*4;
  int row = (int)(oi >> 12);
  int c = (int)(oi & 4095);
  int b = row >> 11; int p = row & 2047;
  int pd = p >> 8, ph = (p>>4)&15, pw = p&15;
  int pz = c >> 8, py = (c>>4)&15, px = c&15;
  size_t src = (((size_t)(b*128 + pd*16+pz)*256) + (size_t)(ph*16+py))*256 + (size_t)(pw*16+px);
  float4 f = *(const float4*)(x+src);
  Xp[oi+0]=f2bf(f.x); Xp[oi+1]=f2bf(f.y); Xp[oi+2]=f2bf(f.z); Xp[oi+3]=f2bf(f.w);
}

// ---------------- assemble h = [cls; sum4(P)] + pos, zero pads
__global__ void assemble_k(const float* __restrict__ P, size_t pstride,
                           const float* __restrict__ cls,
                           const float* __restrict__ pos_e, float* __restrict__ H)
{
  int row = blockIdx.x; int t = threadIdx.x;
  float* hr = H + (size_t)row*EMB;
  if (row >= MROWS) { hr[t]=0.f; hr[t+256]=0.f; hr[t+512]=0.f; return; }
  int b = row / SEQ; int pos = row - b*SEQ;
#pragma unroll
  for (int c0=0;c0<3;++c0) {
    int c = t + c0*256;
    float v;
    if (pos==0) v = cls[c];
    else {
      size_t idx = ((size_t)(b*2048 + pos-1))*EMB + c;
      v = P[idx] + P[pstride+idx] + P[2*pstride+idx] + P[3*pstride+idx];
    }
    hr[c] = v + pos_e[(size_t)pos*EMB + c];
  }
}

// ---------------- layernorm row -> bf16
__global__ __launch_bounds__(256) void ln_k(const float* __restrict__ H,
    const float* __restrict__ gam, const float* __restrict__ bet,
    unsigned short* __restrict__ Y)
{
  int row = blockIdx.x, t = threadIdx.x;
  const float* hr = H + (size_t)row*EMB;
  float v0 = hr[t], v1 = hr[t+256], v2 = hr[t+512];
  float s = v0+v1+v2;
#pragma unroll
  for (int off=32; off>=1; off>>=1) s += __shfl_down(s, off);
  __shared__ float r1[4], r2[4];
  if ((t&63)==0) r1[t>>6] = s;
  __syncthreads();
  float mean = (r1[0]+r1[1]+r1[2]+r1[3]) * (1.f/768.f);
  float d0=v0-mean, d1=v1-mean, d2=v2-mean;
  float q = d0*d0+d1*d1+d2*d2;
#pragma unroll
  for (int off=32; off>=1; off>>=1) q += __shfl_down(q, off);
  if ((t&63)==0) r2[t>>6] = q;
  __syncthreads();
  float rstd = rsqrtf((r2[0]+r2[1]+r2[2]+r2[3])*(1.f/768.f) + 1e-5f);
  unsigned short* yr = Y + (size_t)row*EMB;
  yr[t]     = f2bf(d0*rstd*gam[t]     + bet[t]);
  yr[t+256] = f2bf(d1*rstd*gam[t+256] + bet[t+256]);
  yr[t+512] = f2bf(d2*rstd*gam[t+512] + bet[t+512]);
}

// ---------------- fused: H += sum_{s<S} P[s]; Y = LN(H)
template<int S>
__global__ __launch_bounds__(256) void ln_red_k(float* __restrict__ H,
    const float* __restrict__ P, size_t pstride,
    const float* __restrict__ gam, const float* __restrict__ bet,
    unsigned short* __restrict__ Y)
{
  int row = blockIdx.x, t = threadIdx.x;
  size_t base = (size_t)row*EMB;
  float v[3];
#pragma unroll
  for (int c0=0;c0<3;++c0) {
    size_t idx = base + t + c0*256;
    float h = H[idx];
#pragma unroll
    for (int s=0;s<S;++s) h += P[(size_t)s*pstride + idx];
    H[idx] = h; v[c0] = h;
  }
  float s = v[0]+v[1]+v[2];
#pragma unroll
  for (int off=32; off>=1; off>>=1) s += __shfl_down(s, off);
  __shared__ float r1[4], r2[4];
  if ((t&63)==0) r1[t>>6] = s;
  __syncthreads();
  float mean = (r1[0]+r1[1]+r1[2]+r1[3]) * (1.f/768.f);
  float d0=v[0]-mean, d1=v[1]-mean, d2=v[2]-mean;
  float q = d0*d0+d1*d1+d2*d2;
#pragma unroll
  for (int off=32; off>=1; off>>=1) q += __shfl_down(q, off);
  if ((t&63)==0) r2[t>>6] = q;
  __syncthreads();
  float rstd = rsqrtf((r2[0]+r2[1]+r2[2]+r2[3])*(1.f/768.f) + 1e-5f);
  unsigned short* yr = Y + base;
  yr[t]     = f2bf(d0*rstd*gam[t]     + bet[t]);
  yr[t+256] = f2bf(d1*rstd*gam[t+256] + bet[t+256]);
  yr[t+512] = f2bf(d2*rstd*gam[t+512] + bet[t+512]);
}

// ---------------- final layernorm on cls rows -> fp32 out
template<int S>
__global__ __launch_bounds__(256) void final_ln_red_k(const float* __restrict__ H,
   const float* __restrict__ P, size_t pstride,
   const float* __restrict__ gam, const float* __restrict__ bet, float* __restrict__ out)
{
  int b = blockIdx.x, t = threadIdx.x;
  size_t base = (size_t)(b*SEQ)*EMB;
  float v[3];
#pragma unroll
  for (int c0=0;c0<3;++c0) {
    size_t idx = base + t + c0*256;
    float h = H[idx];
#pragma unroll
    for (int s=0;s<S;++s) h += P[(size_t)s*pstride + idx];
    v[c0] = h;
  }
  float s = v[0]+v[1]+v[2];
#pragma unroll
  for (int off=32; off>=1; off>>=1) s += __shfl_down(s, off);
  __shared__ float r1[4], r2[4];
  if ((t&63)==0) r1[t>>6] = s;
  __syncthreads();
  float mean = (r1[0]+r1[1]+r1[2]+r1[3]) * (1.f/768.f);
  float d0=v[0]-mean, d1=v[1]-mean, d2=v[2]-mean;
  float q = d0*d0+d1*d1+d2*d2;
#pragma unroll
  for (int off=32; off>=1; off>>=1) q += __shfl_down(q, off);
  if ((t&63)==0) r2[t>>6] = q;
  __syncthreads();
  float rstd = rsqrtf((r2[0]+r2[1]+r2[2]+r2[3])*(1.f/768.f) + 1e-5f);
  out[b*EMB + t]     = d0*rstd*gam[t]     + bet[t];
  out[b*EMB + t+256] = d1*rstd*gam[t+256] + bet[t+256];
  out[b*EMB + t+512] = d2*rstd*gam[t+512] + bet[t+512];
}

// ---------------- GEMM: 128x128 tile, 3 LDS buffers, depth-2 prefetch (r8 config)
// MODE 0: bf16 out +bias; 1: bf16 out +bias+gelu; 3: f32 split-partial write
template<int MODE, int NSPLIT>
__global__ __launch_bounds__(256) void gemm_k(
    const unsigned short* __restrict__ A,
    const unsigned short* __restrict__ Bt,
    const float* __restrict__ bias,
    unsigned short* __restrict__ Cb,
    float* __restrict__ Cf,
    int K, int ldc, size_t splitStride)
{
  __shared__ __attribute__((aligned(16))) unsigned short lA[3][128*32];
  __shared__ __attribute__((aligned(16))) unsigned short lB[3][128*32];
  const int tid = threadIdx.x;
  const int w = tid>>6, lane = tid&63, g = lane>>4, l16 = lane&15;
  const int lr = lane>>2;
  const int lcs = (((lane&3) ^ ((lane>>3)&3)))*8;
  const int swz = ((g ^ ((l16>>1)&3)))*8;
  const int nwg = gridDim.x*gridDim.y;
  const int id = blockIdx.y*gridDim.x + blockIdx.x;
  const int q = nwg>>3, r = nwg&7, xc = id&7, si = id>>3;
  const int nid = (xc<r ? xc*(q+1) : r*(q+1)+(xc-r)*q) + si;
  const int tm = nid / gridDim.x;
  const int tn = nid - tm*gridDim.x;
  const int kchunk = K / NSPLIT;
  const int kofs = (NSPLIT>1) ? blockIdx.z * kchunk : 0;
  const unsigned short* Ab = A + (size_t)tm*128*K + kofs;
  const unsigned short* Bb = Bt + (size_t)tn*128*K + kofs;
  const int wm = (w>>1)*64, wn = (w&1)*64;
  f4 acc[4][4] = {};
  const int nkt = kchunk>>5;

  auto STAGE = [&](int buf, int kt){
    const size_t ko = (size_t)(kt*32 + lcs);
    gl_lds16(Ab + (size_t)(w*16 + lr)*K + ko,     ((char*)lA[buf]) + w*1024);
    gl_lds16(Ab + (size_t)((w+4)*16 + lr)*K + ko, ((char*)lA[buf]) + (w+4)*1024);
    gl_lds16(Bb + (size_t)(w*16 + lr)*K + ko,     ((char*)lB[buf]) + w*1024);
    gl_lds16(Bb + (size_t)((w+4)*16 + lr)*K + ko, ((char*)lB[buf]) + (w+4)*1024);
  };

  STAGE(0, 0);
  STAGE(1, 1);
  for (int kt=0; kt<nkt; ++kt) {
    const int cur = kt % 3;
    if (kt+2 < nkt) {
      STAGE((kt+2)%3, kt+2);
      asm volatile("s_waitcnt vmcnt(8)" ::: "memory");
    } else if (kt+1 < nkt) {
      asm volatile("s_waitcnt vmcnt(4)" ::: "memory");
    } else {
      asm volatile("s_waitcnt vmcnt(0)" ::: "memory");
    }
    __builtin_amdgcn_sched_barrier(0);
    __builtin_amdgcn_s_barrier();
    bs8 af[4], bf[4];
#pragma unroll
    for (int mi=0;mi<4;++mi) af[mi] = *(const bs8*)(lA[cur] + (wm+mi*16+l16)*32 + swz);
#pragma unroll
    for (int ni=0;ni<4;++ni) bf[ni] = *(const bs8*)(lB[cur] + (wn+ni*16+l16)*32 + swz);
    asm volatile("s_waitcnt lgkmcnt(0)" ::: "memory");
    __builtin_amdgcn_sched_barrier(0);
    __builtin_amdgcn_s_barrier();
#pragma unroll
    for (int mi=0;mi<4;++mi)
#pragma unroll
      for (int ni=0;ni<4;++ni)
        acc[mi][ni] = __builtin_amdgcn_mfma_f32_16x16x32_bf16(af[mi], bf[ni], acc[mi][ni], 0,0,0);
  }
  const float bscale = (NSPLIT==1 || blockIdx.z==0) ? 1.f : 0.f;
#pragma unroll
  for (int mi=0;mi<4;++mi)
#pragma unroll
    for (int ni=0;ni<4;++ni) {
      int col = tn*128 + wn + ni*16 + l16;
      float bv = bias[col]*bscale;
#pragma unroll
      for (int r0=0;r0<4;++r0) {
        int row = tm*128 + wm + mi*16 + g*4 + r0;
        float val = acc[mi][ni][r0] + bv;
        if (MODE==1) val = gelu_f(val);
        if (MODE<=1) Cb[(size_t)row*ldc + col] = f2bf(val);
        else Cf[(size_t)blockIdx.z*splitStride + (size_t)row*ldc + col] = val;
      }
    }
}

// ---------------- fused dilated attention: Pl aliased onto lK (LDS 35.8 KB),
// NO forced min-waves bound (r10's cap caused scratch spills).
__global__ __launch_bounds__(256) void attn_all_k(
    const unsigned short* __restrict__ qkv,
    unsigned short* __restrict__ O1, float* __restrict__ L1,
    unsigned short* __restrict__ O2, float* __restrict__ L2,
    unsigned short* __restrict__ O3, float* __restrict__ L3)
{
  // lK: 128*72 shorts (18.4KB); lVt: 64*136 shorts (17.4KB); Pl aliases lK
  __shared__ __attribute__((aligned(16))) unsigned short lsm[128*72 + 64*136];
  unsigned short* lK  = lsm;
  unsigned short* lVt = lsm + 128*72;
  const int tid = threadIdx.x;
  const int w = tid>>6, lane = tid&63, g = lane>>4, l16 = lane&15;

  int id = (blockIdx.x & 7)*240 + (blockIdx.x >> 3);
  int R, WSZ, NSEG; unsigned short* OB; float* LB;
  if (id < 960)       { R=1; WSZ=512;  NSEG=5; OB=O1; LB=L1; }
  else if (id < 1536) { id -= 960;  R=2; WSZ=1024; NSEG=3; OB=O2; LB=L2; }
  else                { id -= 1536; R=4; WSZ=2048; NSEG=2; OB=O3; LB=L3; }
  const int qt = id & 7; int rest = id >> 3;
  const int seg = rest % NSEG; const int bh = rest / NSEG;
  const int b = bh / NHEADS, hd = bh % NHEADS;
  const int hr = hd % R;
  const int kbase = seg*WSZ + hr;
  bs8 z = {0,0,0,0,0,0,0,0};

  if (kbase + qt*64*R >= SEQ) {
    size_t ob2 = ((size_t)(b*NSEG + seg)*NHEADS + hd)*512 + qt*64;
    int row = tid>>2, cb = (tid&3)*16;
    *(bs8*)(&OB[(ob2 + row)*64 + cb])     = z;
    *(bs8*)(&OB[(ob2 + row)*64 + cb + 8]) = z;
    if (tid < 64) LB[ob2 + tid] = NEGV;
    return;
  }
  int nvk = (SEQ - 1 - kbase)/R + 1; if (nvk > 512) nvk = 512;
  const int nck = (nvk + 127) >> 7;

  const int j0 = qt*64 + w*16;
  const unsigned short* qkvb = qkv + (size_t)b*SEQ*QKVW;

  bs8 qf0 = z, qf1 = z;
  {
    int qpos = kbase + (j0 + l16)*R;
    if (qpos < SEQ) {
      const unsigned short* qrow = qkvb + (size_t)qpos*QKVW + hd*64 + g*8;
      qf0 = *(const bs8*)(qrow);
      qf1 = *(const bs8*)(qrow + 32);
    }
  }

  const int dbK = tid&7, kkKb = tid>>3;
  const int kkV = tid&127, dbV0 = tid>>7;
  const unsigned short* pK = qkvb + (size_t)(kbase + kkKb*R)*QKVW + EMB + hd*64 + dbK*8;
  const unsigned short* pV = qkvb + (size_t)(kbase + kkV*R)*QKVW + 1536 + hd*64 + dbV0*8;
  const size_t stepIt = (size_t)32*R*QKVW;
  const size_t stepC  = (size_t)128*R*QKVW;
  int ci = 0;
  bs8 kreg[4], vreg[4];
  auto ISSUE = [&](){
    const bool full = (kbase + (ci*128 + 127)*R) < SEQ;
    if (full) {
#pragma unroll
      for (int it=0; it<4; ++it) kreg[it] = *(const bs8*)(pK + (size_t)it*stepIt);
#pragma unroll
      for (int it=0; it<4; ++it) vreg[it] = *(const bs8*)(pV + it*16);
    } else {
      const int cofs = ci*128*R;
#pragma unroll
      for (int it=0; it<4; ++it)
        kreg[it] = (kbase + (kkKb + it*32)*R + cofs < SEQ)
                   ? *(const bs8*)(pK + (size_t)it*stepIt) : z;
      const bool vv = (kbase + kkV*R + cofs) < SEQ;
#pragma unroll
      for (int it=0; it<4; ++it) vreg[it] = vv ? *(const bs8*)(pV + it*16) : z;
    }
    pK += stepC; pV += stepC; ++ci;
  };

  float rm[4], rs[4];
  f4 oacc[4] = {};
#pragma unroll
  for (int r=0;r<4;++r) { rm[r] = NEGV; rs[r] = 0.f; }

  ISSUE();
  for (int c=0; c<nck; ++c) {
    __syncthreads();                // all waves done with PV(c-1): lK(Pl) & lVt free
#pragma unroll
    for (int it=0; it<4; ++it) {
      *(bs8*)(lK + (kkKb + it*32)*72 + dbK*8) = kreg[it];
#pragma unroll
      for (int ii=0; ii<8; ++ii) lVt[((dbV0+it*2)*8+ii)*136 + kkV] = (unsigned short)vreg[it][ii];
    }
    __syncthreads();                // chunk c staged, visible
    if (c+1 < nck) ISSUE();         // next chunk's loads overlap compute

    const bool fullc = (kbase + (c*128 + 127)*R) < SEQ;
    f4 sc[8];
    __builtin_amdgcn_s_setprio(1);
#pragma unroll
    for (int kt=0; kt<8; ++kt) {
      int key = kt*16 + l16;
      bs8 kf0 = *(const bs8*)(lK + key*72 + g*8);
      bs8 kf1 = *(const bs8*)(lK + key*72 + 32 + g*8);
      f4 acc = {0.f,0.f,0.f,0.f};
      acc = __builtin_amdgcn_mfma_f32_16x16x32_bf16(qf0, kf0, acc, 0,0,0);
      acc = __builtin_amdgcn_mfma_f32_16x16x32_bf16(qf1, kf1, acc, 0,0,0);
      sc[kt] = acc;
    }
    __builtin_amdgcn_s_setprio(0);
    __syncthreads();                // all waves done reading lK -> Pl may overwrite it
    if (fullc) {
#pragma unroll
      for (int kt=0; kt<8; ++kt)
#pragma unroll
        for (int r=0;r<4;++r) sc[kt][r] *= 0.125f;
    } else {
#pragma unroll
      for (int kt=0; kt<8; ++kt) {
        bool kvld = (kbase + (c*128 + kt*16 + l16)*R) < SEQ;
#pragma unroll
        for (int r=0;r<4;++r) sc[kt][r] = kvld ? sc[kt][r]*0.125f : NEGV;
      }
    }
    float scl[4];
#pragma unroll
    for (int r=0;r<4;++r) {
      float mx = sc[0][r];
#pragma unroll
      for (int kt=1;kt<8;++kt) mx = fmaxf(mx, sc[kt][r]);
      mx = fmaxf(mx, __shfl_xor(mx, 1));
      mx = fmaxf(mx, __shfl_xor(mx, 2));
      mx = fmaxf(mx, __shfl_xor(mx, 4));
      mx = fmaxf(mx, __shfl_xor(mx, 8));
      float mn = fmaxf(rm[r], mx);
      scl[r] = __expf(rm[r] - mn);
      rm[r] = mn;
    }
#pragma unroll
    for (int r=0;r<4;++r) {
      float sm = 0.f;
#pragma unroll
      for (int kt=0;kt<8;++kt) { float p = __expf(sc[kt][r] - rm[r]); sc[kt][r] = p; sm += p; }
      rs[r] = rs[r]*scl[r] + sm;
    }
    if (scl[0]<1.f || scl[1]<1.f || scl[2]<1.f || scl[3]<1.f) {
#pragma unroll
      for (int dt=0; dt<4; ++dt)
#pragma unroll
        for (int r=0;r<4;++r) oacc[dt][r] *= scl[r];
    }
    // Pl aliases lK: per-wave region [w*16..w*16+15] rows of stride 136
    unsigned short* Plw = lK + w*16*136;
#pragma unroll
    for (int kt=0;kt<8;++kt)
#pragma unroll
      for (int r=0;r<4;++r)
        Plw[(g*4+r)*136 + kt*16+l16] = f2bf_fast(sc[kt][r]);
    __builtin_amdgcn_s_setprio(1);
#pragma unroll
    for (int ks=0; ks<4; ++ks) {
      bs8 pa = *(const bs8*)(Plw + l16*136 + ks*32 + g*8);
#pragma unroll
      for (int dt=0; dt<4; ++dt) {
        bs8 vb = *(const bs8*)(lVt + (dt*16+l16)*136 + ks*32 + g*8);
        oacc[dt] = __builtin_amdgcn_mfma_f32_16x16x32_bf16(pa, vb, oacc[dt], 0,0,0);
      }
    }
    __builtin_amdgcn_s_setprio(0);
  }

#pragma unroll
  for (int r=0;r<4;++r) {
    float s = rs[r];
    s += __shfl_xor(s, 1); s += __shfl_xor(s, 2);
    s += __shfl_xor(s, 4); s += __shfl_xor(s, 8);
    rs[r] = s;
  }

  size_t obase = ((size_t)(b*NSEG + seg)*NHEADS + hd)*512;
#pragma unroll
  for (int dt=0; dt<4; ++dt)
#pragma unroll
    for (int r=0;r<4;++r) {
      int j = j0 + g*4 + r;
      OB[(obase + j)*64 + dt*16 + l16] = f2bf(oacc[dt][r] / rs[r]);
    }
  if (l16 == 0) {
#pragma unroll
    for (int r=0;r<4;++r) LB[obase + j0 + g*4 + r] = rm[r] + __logf(rs[r]);
  }
}

// ---------------- combine 3 branches via lse softmax -> attn bf16 (MPAD,768)
__global__ __launch_bounds__(256) void attn_combine_k(
   const unsigned short* __restrict__ o1, const float* __restrict__ l1,
   const unsigned short* __restrict__ o2, const float* __restrict__ l2,
   const unsigned short* __restrict__ o3, const float* __restrict__ l3,
   unsigned short* __restrict__ attn)
{
  int row = blockIdx.x; int t = threadIdx.x;
  unsigned short* arow = attn + (size_t)row*EMB;
  if (row >= MROWS) { arow[t]=0; arow[t+256]=0; arow[t+512]=0; return; }
  int b = row / SEQ, pos = row - (row/SEQ)*SEQ;
#pragma unroll
  for (int c0=0; c0<3; ++c0) {
    int cc = t + c0*256;
    int hd = cc >> 6, d = cc & 63;
    float L0,L1v,L2v,O0,O1v,O2v;
    {
      int seg = pos >> 9; int j = pos & 511;
      size_t base = ((size_t)(b*5 + seg)*NHEADS + hd)*512 + j;
      L0 = l1[base]; O0 = bf2f(o1[base*64 + d]);
    }
    if ((pos & 1) == (hd & 1)) {
      int seg = pos >> 10; int j = ((pos & 1023) - (hd&1)) >> 1;
      size_t base = ((size_t)(b*3 + seg)*NHEADS + hd)*512 + j;
      L1v = l2[base]; O1v = bf2f(o2[base*64 + d]);
    } else { L1v = NEGV; O1v = 0.f; }
    if ((pos & 3) == (hd & 3)) {
      int seg = pos >> 11; int j = ((pos & 2047) - (hd&3)) >> 2;
      size_t base = ((size_t)(b*2 + seg)*NHEADS + hd)*512 + j;
      L2v = l3[base]; O2v = bf2f(o3[base*64 + d]);
    } else { L2v = NEGV; O2v = 0.f; }
    float m = fmaxf(L0, fmaxf(L1v, L2v));
    float e0 = __expf(L0-m), e1 = __expf(L1v-m), e2 = __expf(L2v-m);
    float inv = 1.f/(e0+e1+e2);
    arow[cc] = f2bf((e0*O0+e1*O1v+e2*O2v)*inv);
  }
}

extern "C" void kernel_launch(void* const* d_in, const int* in_sizes, int n_in,
                              void* d_out, int out_size, void* d_ws, size_t ws_size,
                              hipStream_t stream) {
  const float* x       = (const float*)d_in[0];
  const float* conv_w  = (const float*)d_in[1];
  const float* conv_b  = (const float*)d_in[2];
  const float* cls     = (const float*)d_in[3];
  const float* pos_e   = (const float*)d_in[4];
  const float* ln1_g   = (const float*)d_in[5];
  const float* ln1_b   = (const float*)d_in[6];
  const float* wq      = (const float*)d_in[7];
  const float* bq      = (const float*)d_in[8];
  const float* wk      = (const float*)d_in[9];
  const float* bk      = (const float*)d_in[10];
  const float* wv      = (const float*)d_in[11];
  const float* bv      = (const float*)d_in[12];
  const float* wo      = (const float*)d_in[13];
  const float* bo      = (const float*)d_in[14];
  const float* ln2_g   = (const float*)d_in[15];
  const float* ln2_b   = (const float*)d_in[16];
  const float* w1      = (const float*)d_in[17];
  const float* b1      = (const float*)d_in[18];
  const float* w2      = (const float*)d_in[19];
  const float* b2      = (const float*)d_in[20];
  const float* nf_g    = (const float*)d_in[21];
  const float* nf_b    = (const float*)d_in[22];

  char* ws = (char*)d_ws;
  size_t off = 0;
  auto alloc = [&](size_t bytes)->char* {
    char* p = ws + off; off += (bytes + 255) & ~(size_t)255; return p;
  };
  unsigned short* wqkv_t = (unsigned short*)alloc((size_t)12*2304*768*2);
  unsigned short* wo_t   = (unsigned short*)alloc((size_t)12*768*768*2);
  unsigned short* w1_t   = (unsigned short*)alloc((size_t)12*3072*768*2);
  unsigned short* w2_t   = (unsigned short*)alloc((size_t)12*768*3072*2);
  unsigned short* cw_b   = (unsigned short*)alloc((size_t)768*4096*2);
  float* bqkv            = (float*)alloc((size_t)12*2304*4);
  unsigned short* Xp     = (unsigned short*)alloc((size_t)4096*4096*2);
  float* H               = (float*)alloc((size_t)MPAD*768*4);
  float* P               = (float*)alloc((size_t)4*MPAD*768*4);
  unsigned short* Y      = (unsigned short*)alloc((size_t)MPAD*768*2);
  unsigned short* QKV    = (unsigned short*)alloc((size_t)MPAD*2304*2);
  unsigned short* ATT    = (unsigned short*)alloc((size_t)MPAD*768*2);
  unsigned short* Y2     = (unsigned short*)alloc((size_t)MPAD*3072*2);
  unsigned short* O1 = (unsigned short*)alloc((size_t)2*5*12*512*64*2);
  unsigned short* O2 = (unsigned short*)alloc((size_t)2*3*12*512*64*2);
  unsigned short* O3 = (unsigned short*)alloc((size_t)2*2*12*512*64*2);
  float* L1 = (float*)alloc((size_t)2*5*12*512*4);
  float* L2 = (float*)alloc((size_t)2*3*12*512*4);
  float* L3 = (float*)alloc((size_t)2*2*12*512*4);
  const size_t PSTR = (size_t)MPAD*768;

  dim3 tb(32,8);
  wtr_k<<<dim3(24,24,12), tb, 0, stream>>>(wq, wqkv_t, 768, 768, 2304, 0);
  wtr_k<<<dim3(24,24,12), tb, 0, stream>>>(wk, wqkv_t, 768, 768, 2304, 768);
  wtr_k<<<dim3(24,24,12), tb, 0, stream>>>(wv, wqkv_t, 768, 768, 2304, 1536);
  wtr_k<<<dim3(24,24,12), tb, 0, stream>>>(wo, wo_t, 768, 768, 768, 0);
  wtr_k<<<dim3(24,96,12), tb, 0, stream>>>(w1, w1_t, 768, 3072, 3072, 0);
  wtr_k<<<dim3(96,24,12), tb, 0, stream>>>(w2, w2_t, 3072, 768, 768, 0);
  castconv_k<<<3072,256,0,stream>>>(conv_w, cw_b);
  biascat_k<<<108,256,0,stream>>>(bq,bk,bv,bqkv);
  patchify_k<<<16384,256,0,stream>>>(x, Xp);
  gemm_k<3,4><<<dim3(6,32,4),256,0,stream>>>(Xp, cw_b, conv_b, nullptr, P, 4096, 768, PSTR);
  assemble_k<<<MPAD,256,0,stream>>>(P, PSTR, cls, pos_e, H);

  for (int l=0;l<12;++l) {
    if (l==0) ln_k<<<MPAD,256,0,stream>>>(H, ln1_g, ln1_b, Y);
    else ln_red_k<2><<<MPAD,256,0,stream>>>(H, P, PSTR, ln1_g + l*768, ln1_b + l*768, Y);
    gemm_k<0,1><<<dim3(18,33),256,0,stream>>>(Y, wqkv_t + (size_t)l*2304*768, bqkv + l*2304, QKV, nullptr, 768, 2304, 0);
    attn_all_k<<<1920,256,0,stream>>>(QKV, O1,L1,O2,L2,O3,L3);
    attn_combine_k<<<MPAD,256,0,stream>>>(O1,L1,O2,L2,O3,L3, ATT);
    gemm_k<3,2><<<dim3(6,33,2),256,0,stream>>>(ATT, wo_t + (size_t)l*768*768, bo + l*768, nullptr, P, 768, 768, PSTR);
    ln_red_k<2><<<MPAD,256,0,stream>>>(H, P, PSTR, ln2_g + l*768, ln2_b + l*768, Y);
    gemm_k<1,1><<<dim3(24,33),256,0,stream>>>(Y, w1_t + (size_t)l*3072*768, b1 + l*3072, Y2, nullptr, 768, 3072, 0);
    gemm_k<3,2><<<dim3(6,33,2),256,0,stream>>>(Y2, w2_t + (size_t)l*768*3072, b2 + l*768, nullptr, P, 3072, 768, PSTR);
  }
  final_ln_red_k<2><<<2,256,0,stream>>>(H, P, PSTR, nf_g, nf_b, (float*)d_out);
}

// Round 12
// 2664.345 us; speedup vs baseline: 1.1249x; 1.0314x over previous
//
#include <hip/hip_runtime.h>
#include <math.h>

#define SEQ 2049
#define EMB 768
#define NHEADS 12
#define QKVW 2304
#define MROWS 4098
#define MPAD 4224
#define NEGV -1000000000.0f

typedef short bs8 __attribute__((ext_vector_type(8)));
typedef float f4 __attribute__((ext_vector_type(4)));

__device__ __forceinline__ unsigned short f2bf(float f){
  union { float f; unsigned u; } x; x.f = f;
  unsigned r = x.u + 0x7fffu + ((x.u >> 16) & 1u);
  return (unsigned short)(r >> 16);
}
__device__ __forceinline__ unsigned short f2bf_fast(float f){
  union { float f; unsigned u; } x; x.f = f;
  return (unsigned short)((x.u + 0x8000u) >> 16);
}
__device__ __forceinline__ float bf2f(unsigned short u){
  union { unsigned u; float f; } x; x.u = ((unsigned)u) << 16; return x.f;
}

__device__ __forceinline__ float gelu_f(float x){
  float ax = fabsf(x)*0.70710678f;
  float t = 1.f/(1.f + 0.3275911f*ax);
  float p = t*(0.254829592f + t*(-0.284496736f + t*(1.421413741f
            + t*(-1.453152027f + t*1.061405429f))));
  float erfv = 1.f - p*__expf(-ax*ax);
  float s = (x >= 0.f) ? erfv : -erfv;
  return 0.5f*x*(1.f + s);
}

__device__ __forceinline__ void gl_lds16(const void* g, void* l){
  __builtin_amdgcn_global_load_lds((const __attribute__((address_space(1))) void*)g,
                                   (__attribute__((address_space(3))) void*)l, 16, 0, 0);
}

// ---------------- weight transpose fp32 (L,K,N) -> bf16 dst[(l*LD+NOFF+n)*K+k]
__global__ void wtr_k(const float* __restrict__ src, unsigned short* __restrict__ dst,
                      int K, int N, int LD, int NOFF)
{
  __shared__ float tile[32][33];
  int k0 = blockIdx.x*32, n0 = blockIdx.y*32, z = blockIdx.z;
  int tx = threadIdx.x, ty = threadIdx.y;
  const float* s = src + (size_t)z*K*N;
#pragma unroll
  for (int i=0;i<4;++i)
    tile[ty*4+i][tx] = s[(size_t)(k0+ty*4+i)*N + n0+tx];
  __syncthreads();
  unsigned short* dz = dst + ((size_t)z*LD + NOFF)*K;
#pragma unroll
  for (int i=0;i<4;++i)
    dz[(size_t)(n0+ty*4+i)*K + k0+tx] = f2bf(tile[tx][ty*4+i]);
}

__global__ void castconv_k(const float* __restrict__ src, unsigned short* __restrict__ dst){
  size_t i = ((size_t)blockIdx.x*256 + threadIdx.x)*4;
  float4 f = *(const float4*)(src+i);
  dst[i+0]=f2bf(f.x); dst[i+1]=f2bf(f.y); dst[i+2]=f2bf(f.z); dst[i+3]=f2bf(f.w);
}

__global__ void biascat_k(const float* __restrict__ bq, const float* __restrict__ bk,
                          const float* __restrict__ bv, float* __restrict__ dst){
  int i = blockIdx.x*256+threadIdx.x;
  int l = i/QKVW, c = i%QKVW;
  float v = (c<768) ? bq[l*768+c] : (c<1536 ? bk[l*768+c-768] : bv[l*768+c-1536]);
  dst[i] = v;
}

// ---------------- patch extraction
__global__ void patchify_k(const float* __restrict__ x, unsigned short* __restrict__ Xp)
{
  size_t gid = (size_t)blockIdx.x*256 + threadIdx.x;
  size_t oi = gid*4;
  int row = (int)(oi >> 12);
  int c = (int)(oi & 4095);
  int b = row >> 11; int p = row & 2047;
  int pd = p >> 8, ph = (p>>4)&15, pw = p&15;
  int pz = c >> 8, py = (c>>4)&15, px = c&15;
  size_t src = (((size_t)(b*128 + pd*16+pz)*256) + (size_t)(ph*16+py))*256 + (size_t)(pw*16+px);
  float4 f = *(const float4*)(x+src);
  Xp[oi+0]=f2bf(f.x); Xp[oi+1]=f2bf(f.y); Xp[oi+2]=f2bf(f.z); Xp[oi+3]=f2bf(f.w);
}

// ---------------- assemble h = [cls; sum4(P)] + pos, zero pads
__global__ void assemble_k(const float* __restrict__ P, size_t pstride,
                           const float* __restrict__ cls,
                           const float* __restrict__ pos_e, float* __restrict__ H)
{
  int row = blockIdx.x; int t = threadIdx.x;
  float* hr = H + (size_t)row*EMB;
  if (row >= MROWS) { hr[t]=0.f; hr[t+256]=0.f; hr[t+512]=0.f; return; }
  int b = row / SEQ; int pos = row - b*SEQ;
#pragma unroll
  for (int c0=0;c0<3;++c0) {
    int c = t + c0*256;
    float v;
    if (pos==0) v = cls[c];
    else {
      size_t idx = ((size_t)(b*2048 + pos-1))*EMB + c;
      v = P[idx] + P[pstride+idx] + P[2*pstride+idx] + P[3*pstride+idx];
    }
    hr[c] = v + pos_e[(size_t)pos*EMB + c];
  }
}

// ---------------- layernorm row -> bf16
__global__ __launch_bounds__(256) void ln_k(const float* __restrict__ H,
    const float* __restrict__ gam, const float* __restrict__ bet,
    unsigned short* __restrict__ Y)
{
  int row = blockIdx.x, t = threadIdx.x;
  const float* hr = H + (size_t)row*EMB;
  float v0 = hr[t], v1 = hr[t+256], v2 = hr[t+512];
  float s = v0+v1+v2;
#pragma unroll
  for (int off=32; off>=1; off>>=1) s += __shfl_down(s, off);
  __shared__ float r1[4], r2[4];
  if ((t&63)==0) r1[t>>6] = s;
  __syncthreads();
  float mean = (r1[0]+r1[1]+r1[2]+r1[3]) * (1.f/768.f);
  float d0=v0-mean, d1=v1-mean, d2=v2-mean;
  float q = d0*d0+d1*d1+d2*d2;
#pragma unroll
  for (int off=32; off>=1; off>>=1) q += __shfl_down(q, off);
  if ((t&63)==0) r2[t>>6] = q;
  __syncthreads();
  float rstd = rsqrtf((r2[0]+r2[1]+r2[2]+r2[3])*(1.f/768.f) + 1e-5f);
  unsigned short* yr = Y + (size_t)row*EMB;
  yr[t]     = f2bf(d0*rstd*gam[t]     + bet[t]);
  yr[t+256] = f2bf(d1*rstd*gam[t+256] + bet[t+256]);
  yr[t+512] = f2bf(d2*rstd*gam[t+512] + bet[t+512]);
}

// ---------------- fused: H += sum_{s<S} P[s]; Y = LN(H)
template<int S>
__global__ __launch_bounds__(256) void ln_red_k(float* __restrict__ H,
    const float* __restrict__ P, size_t pstride,
    const float* __restrict__ gam, const float* __restrict__ bet,
    unsigned short* __restrict__ Y)
{
  int row = blockIdx.x, t = threadIdx.x;
  size_t base = (size_t)row*EMB;
  float v[3];
#pragma unroll
  for (int c0=0;c0<3;++c0) {
    size_t idx = base + t + c0*256;
    float h = H[idx];
#pragma unroll
    for (int s=0;s<S;++s) h += P[(size_t)s*pstride + idx];
    H[idx] = h; v[c0] = h;
  }
  float s = v[0]+v[1]+v[2];
#pragma unroll
  for (int off=32; off>=1; off>>=1) s += __shfl_down(s, off);
  __shared__ float r1[4], r2[4];
  if ((t&63)==0) r1[t>>6] = s;
  __syncthreads();
  float mean = (r1[0]+r1[1]+r1[2]+r1[3]) * (1.f/768.f);
  float d0=v[0]-mean, d1=v[1]-mean, d2=v[2]-mean;
  float q = d0*d0+d1*d1+d2*d2;
#pragma unroll
  for (int off=32; off>=1; off>>=1) q += __shfl_down(q, off);
  if ((t&63)==0) r2[t>>6] = q;
  __syncthreads();
  float rstd = rsqrtf((r2[0]+r2[1]+r2[2]+r2[3])*(1.f/768.f) + 1e-5f);
  unsigned short* yr = Y + base;
  yr[t]     = f2bf(d0*rstd*gam[t]     + bet[t]);
  yr[t+256] = f2bf(d1*rstd*gam[t+256] + bet[t+256]);
  yr[t+512] = f2bf(d2*rstd*gam[t+512] + bet[t+512]);
}

// ---------------- final layernorm on cls rows -> fp32 out
template<int S>
__global__ __launch_bounds__(256) void final_ln_red_k(const float* __restrict__ H,
   const float* __restrict__ P, size_t pstride,
   const float* __restrict__ gam, const float* __restrict__ bet, float* __restrict__ out)
{
  int b = blockIdx.x, t = threadIdx.x;
  size_t base = (size_t)(b*SEQ)*EMB;
  float v[3];
#pragma unroll
  for (int c0=0;c0<3;++c0) {
    size_t idx = base + t + c0*256;
    float h = H[idx];
#pragma unroll
    for (int s=0;s<S;++s) h += P[(size_t)s*pstride + idx];
    v[c0] = h;
  }
  float s = v[0]+v[1]+v[2];
#pragma unroll
  for (int off=32; off>=1; off>>=1) s += __shfl_down(s, off);
  __shared__ float r1[4], r2[4];
  if ((t&63)==0) r1[t>>6] = s;
  __syncthreads();
  float mean = (r1[0]+r1[1]+r1[2]+r1[3]) * (1.f/768.f);
  float d0=v[0]-mean, d1=v[1]-mean, d2=v[2]-mean;
  float q = d0*d0+d1*d1+d2*d2;
#pragma unroll
  for (int off=32; off>=1; off>>=1) q += __shfl_down(q, off);
  if ((t&63)==0) r2[t>>6] = q;
  __syncthreads();
  float rstd = rsqrtf((r2[0]+r2[1]+r2[2]+r2[3])*(1.f/768.f) + 1e-5f);
  out[b*EMB + t]     = d0*rstd*gam[t]     + bet[t];
  out[b*EMB + t+256] = d1*rstd*gam[t+256] + bet[t+256];
  out[b*EMB + t+512] = d2*rstd*gam[t+512] + bet[t+512];
}

// ---------------- GEMM: 128x128 tile, 512 threads / 8 waves (each 64x32 out),
// 3 LDS buffers, depth-2 prefetch, counted vmcnt, XOR-swizzled LDS.
// 24 waves/CU (3 blocks x 8) for latency hiding.
// MODE 0: bf16 out +bias; 1: bf16 out +bias+gelu; 3: f32 split-partial write
template<int MODE, int NSPLIT>
__global__ __launch_bounds__(512) void gemm_k(
    const unsigned short* __restrict__ A,
    const unsigned short* __restrict__ Bt,
    const float* __restrict__ bias,
    unsigned short* __restrict__ Cb,
    float* __restrict__ Cf,
    int K, int ldc, size_t splitStride)
{
  __shared__ __attribute__((aligned(16))) unsigned short lA[3][128*32];
  __shared__ __attribute__((aligned(16))) unsigned short lB[3][128*32];
  const int tid = threadIdx.x;
  const int w = tid>>6, lane = tid&63, g = lane>>4, l16 = lane&15;
  const int lr = lane>>2;
  const int lcs = (((lane&3) ^ ((lane>>3)&3)))*8;   // pre-swizzled source col-group
  const int swz = ((g ^ ((l16>>1)&3)))*8;           // matching read offset
  const int nwg = gridDim.x*gridDim.y;
  const int id = blockIdx.y*gridDim.x + blockIdx.x;
  const int q = nwg>>3, r = nwg&7, xc = id&7, si = id>>3;
  const int nid = (xc<r ? xc*(q+1) : r*(q+1)+(xc-r)*q) + si;
  const int tm = nid / gridDim.x;
  const int tn = nid - tm*gridDim.x;
  const int kchunk = K / NSPLIT;
  const int kofs = (NSPLIT>1) ? blockIdx.z * kchunk : 0;
  const unsigned short* Ab = A + (size_t)tm*128*K + kofs;
  const unsigned short* Bb = Bt + (size_t)tn*128*K + kofs;
  const int wm = (w>>2)*64, wn = (w&3)*32;          // 2x4 wave grid, 64x32 per wave
  f4 acc[4][2] = {};
  const int nkt = kchunk>>5;

  auto STAGE = [&](int buf, int kt){
    const size_t ko = (size_t)(kt*32 + lcs);
    gl_lds16(Ab + (size_t)(w*16 + lr)*K + ko, ((char*)lA[buf]) + w*1024);
    gl_lds16(Bb + (size_t)(w*16 + lr)*K + ko, ((char*)lB[buf]) + w*1024);
  };

  STAGE(0, 0);
  STAGE(1, 1);
  for (int kt=0; kt<nkt; ++kt) {
    const int cur = kt % 3;
    if (kt+2 < nkt) {
      STAGE((kt+2)%3, kt+2);
      asm volatile("s_waitcnt vmcnt(4)" ::: "memory");   // kt's 2 loads done
    } else if (kt+1 < nkt) {
      asm volatile("s_waitcnt vmcnt(2)" ::: "memory");
    } else {
      asm volatile("s_waitcnt vmcnt(0)" ::: "memory");
    }
    __builtin_amdgcn_sched_barrier(0);
    __builtin_amdgcn_s_barrier();          // buf[cur] ready for all waves
    bs8 af[4], bf[2];
#pragma unroll
    for (int mi=0;mi<4;++mi) af[mi] = *(const bs8*)(lA[cur] + (wm+mi*16+l16)*32 + swz);
#pragma unroll
    for (int ni=0;ni<2;++ni) bf[ni] = *(const bs8*)(lB[cur] + (wn+ni*16+l16)*32 + swz);
    asm volatile("s_waitcnt lgkmcnt(0)" ::: "memory");
    __builtin_amdgcn_sched_barrier(0);
    __builtin_amdgcn_s_barrier();          // all reads of buf[cur] done -> reusable
#pragma unroll
    for (int mi=0;mi<4;++mi)
#pragma unroll
      for (int ni=0;ni<2;++ni)
        acc[mi][ni] = __builtin_amdgcn_mfma_f32_16x16x32_bf16(af[mi], bf[ni], acc[mi][ni], 0,0,0);
  }
  const float bscale = (NSPLIT==1 || blockIdx.z==0) ? 1.f : 0.f;
#pragma unroll
  for (int mi=0;mi<4;++mi)
#pragma unroll
    for (int ni=0;ni<2;++ni) {
      int col = tn*128 + wn + ni*16 + l16;
      float bv = bias[col]*bscale;
#pragma unroll
      for (int r0=0;r0<4;++r0) {
        int row = tm*128 + wm + mi*16 + g*4 + r0;
        float val = acc[mi][ni][r0] + bv;
        if (MODE==1) val = gelu_f(val);
        if (MODE<=1) Cb[(size_t)row*ldc + col] = f2bf(val);
        else Cf[(size_t)blockIdx.z*splitStride + (size_t)row*ldc + col] = val;
      }
    }
}

// ---------------- fused dilated attention (unchanged from r11, passed)
__global__ __launch_bounds__(256) void attn_all_k(
    const unsigned short* __restrict__ qkv,
    unsigned short* __restrict__ O1, float* __restrict__ L1,
    unsigned short* __restrict__ O2, float* __restrict__ L2,
    unsigned short* __restrict__ O3, float* __restrict__ L3)
{
  __shared__ __attribute__((aligned(16))) unsigned short lsm[128*72 + 64*136];
  unsigned short* lK  = lsm;
  unsigned short* lVt = lsm + 128*72;
  const int tid = threadIdx.x;
  const int w = tid>>6, lane = tid&63, g = lane>>4, l16 = lane&15;

  int id = (blockIdx.x & 7)*240 + (blockIdx.x >> 3);
  int R, WSZ, NSEG; unsigned short* OB; float* LB;
  if (id < 960)       { R=1; WSZ=512;  NSEG=5; OB=O1; LB=L1; }
  else if (id < 1536) { id -= 960;  R=2; WSZ=1024; NSEG=3; OB=O2; LB=L2; }
  else                { id -= 1536; R=4; WSZ=2048; NSEG=2; OB=O3; LB=L3; }
  const int qt = id & 7; int rest = id >> 3;
  const int seg = rest % NSEG; const int bh = rest / NSEG;
  const int b = bh / NHEADS, hd = bh % NHEADS;
  const int hr = hd % R;
  const int kbase = seg*WSZ + hr;
  bs8 z = {0,0,0,0,0,0,0,0};

  if (kbase + qt*64*R >= SEQ) {
    size_t ob2 = ((size_t)(b*NSEG + seg)*NHEADS + hd)*512 + qt*64;
    int row = tid>>2, cb = (tid&3)*16;
    *(bs8*)(&OB[(ob2 + row)*64 + cb])     = z;
    *(bs8*)(&OB[(ob2 + row)*64 + cb + 8]) = z;
    if (tid < 64) LB[ob2 + tid] = NEGV;
    return;
  }
  int nvk = (SEQ - 1 - kbase)/R + 1; if (nvk > 512) nvk = 512;
  const int nck = (nvk + 127) >> 7;

  const int j0 = qt*64 + w*16;
  const unsigned short* qkvb = qkv + (size_t)b*SEQ*QKVW;

  bs8 qf0 = z, qf1 = z;
  {
    int qpos = kbase + (j0 + l16)*R;
    if (qpos < SEQ) {
      const unsigned short* qrow = qkvb + (size_t)qpos*QKVW + hd*64 + g*8;
      qf0 = *(const bs8*)(qrow);
      qf1 = *(const bs8*)(qrow + 32);
    }
  }

  const int dbK = tid&7, kkKb = tid>>3;
  const int kkV = tid&127, dbV0 = tid>>7;
  const unsigned short* pK = qkvb + (size_t)(kbase + kkKb*R)*QKVW + EMB + hd*64 + dbK*8;
  const unsigned short* pV = qkvb + (size_t)(kbase + kkV*R)*QKVW + 1536 + hd*64 + dbV0*8;
  const size_t stepIt = (size_t)32*R*QKVW;
  const size_t stepC  = (size_t)128*R*QKVW;
  int ci = 0;
  bs8 kreg[4], vreg[4];
  auto ISSUE = [&](){
    const bool full = (kbase + (ci*128 + 127)*R) < SEQ;
    if (full) {
#pragma unroll
      for (int it=0; it<4; ++it) kreg[it] = *(const bs8*)(pK + (size_t)it*stepIt);
#pragma unroll
      for (int it=0; it<4; ++it) vreg[it] = *(const bs8*)(pV + it*16);
    } else {
      const int cofs = ci*128*R;
#pragma unroll
      for (int it=0; it<4; ++it)
        kreg[it] = (kbase + (kkKb + it*32)*R + cofs < SEQ)
                   ? *(const bs8*)(pK + (size_t)it*stepIt) : z;
      const bool vv = (kbase + kkV*R + cofs) < SEQ;
#pragma unroll
      for (int it=0; it<4; ++it) vreg[it] = vv ? *(const bs8*)(pV + it*16) : z;
    }
    pK += stepC; pV += stepC; ++ci;
  };

  float rm[4], rs[4];
  f4 oacc[4] = {};
#pragma unroll
  for (int r=0;r<4;++r) { rm[r] = NEGV; rs[r] = 0.f; }

  ISSUE();
  for (int c=0; c<nck; ++c) {
    __syncthreads();
#pragma unroll
    for (int it=0; it<4; ++it) {
      *(bs8*)(lK + (kkKb + it*32)*72 + dbK*8) = kreg[it];
#pragma unroll
      for (int ii=0; ii<8; ++ii) lVt[((dbV0+it*2)*8+ii)*136 + kkV] = (unsigned short)vreg[it][ii];
    }
    __syncthreads();
    if (c+1 < nck) ISSUE();

    const bool fullc = (kbase + (c*128 + 127)*R) < SEQ;
    f4 sc[8];
    __builtin_amdgcn_s_setprio(1);
#pragma unroll
    for (int kt=0; kt<8; ++kt) {
      int key = kt*16 + l16;
      bs8 kf0 = *(const bs8*)(lK + key*72 + g*8);
      bs8 kf1 = *(const bs8*)(lK + key*72 + 32 + g*8);
      f4 acc = {0.f,0.f,0.f,0.f};
      acc = __builtin_amdgcn_mfma_f32_16x16x32_bf16(qf0, kf0, acc, 0,0,0);
      acc = __builtin_amdgcn_mfma_f32_16x16x32_bf16(qf1, kf1, acc, 0,0,0);
      sc[kt] = acc;
    }
    __builtin_amdgcn_s_setprio(0);
    __syncthreads();                // all waves done reading lK -> Pl may overwrite it
    if (fullc) {
#pragma unroll
      for (int kt=0; kt<8; ++kt)
#pragma unroll
        for (int r=0;r<4;++r) sc[kt][r] *= 0.125f;
    } else {
#pragma unroll
      for (int kt=0; kt<8; ++kt) {
        bool kvld = (kbase + (c*128 + kt*16 + l16)*R) < SEQ;
#pragma unroll
        for (int r=0;r<4;++r) sc[kt][r] = kvld ? sc[kt][r]*0.125f : NEGV;
      }
    }
    float scl[4];
#pragma unroll
    for (int r=0;r<4;++r) {
      float mx = sc[0][r];
#pragma unroll
      for (int kt=1;kt<8;++kt) mx = fmaxf(mx, sc[kt][r]);
      mx = fmaxf(mx, __shfl_xor(mx, 1));
      mx = fmaxf(mx, __shfl_xor(mx, 2));
      mx = fmaxf(mx, __shfl_xor(mx, 4));
      mx = fmaxf(mx, __shfl_xor(mx, 8));
      float mn = fmaxf(rm[r], mx);
      scl[r] = __expf(rm[r] - mn);
      rm[r] = mn;
    }
#pragma unroll
    for (int r=0;r<4;++r) {
      float sm = 0.f;
#pragma unroll
      for (int kt=0;kt<8;++kt) { float p = __expf(sc[kt][r] - rm[r]); sc[kt][r] = p; sm += p; }
      rs[r] = rs[r]*scl[r] + sm;
    }
    if (scl[0]<1.f || scl[1]<1.f || scl[2]<1.f || scl[3]<1.f) {
#pragma unroll
      for (int dt=0; dt<4; ++dt)
#pragma unroll
        for (int r=0;r<4;++r) oacc[dt][r] *= scl[r];
    }
    unsigned short* Plw = lK + w*16*136;
#pragma unroll
    for (int kt=0;kt<8;++kt)
#pragma unroll
      for (int r=0;r<4;++r)
        Plw[(g*4+r)*136 + kt*16+l16] = f2bf_fast(sc[kt][r]);
    __builtin_amdgcn_s_setprio(1);
#pragma unroll
    for (int ks=0; ks<4; ++ks) {
      bs8 pa = *(const bs8*)(Plw + l16*136 + ks*32 + g*8);
#pragma unroll
      for (int dt=0; dt<4; ++dt) {
        bs8 vb = *(const bs8*)(lVt + (dt*16+l16)*136 + ks*32 + g*8);
        oacc[dt] = __builtin_amdgcn_mfma_f32_16x16x32_bf16(pa, vb, oacc[dt], 0,0,0);
      }
    }
    __builtin_amdgcn_s_setprio(0);
  }

#pragma unroll
  for (int r=0;r<4;++r) {
    float s = rs[r];
    s += __shfl_xor(s, 1); s += __shfl_xor(s, 2);
    s += __shfl_xor(s, 4); s += __shfl_xor(s, 8);
    rs[r] = s;
  }

  size_t obase = ((size_t)(b*NSEG + seg)*NHEADS + hd)*512;
#pragma unroll
  for (int dt=0; dt<4; ++dt)
#pragma unroll
    for (int r=0;r<4;++r) {
      int j = j0 + g*4 + r;
      OB[(obase + j)*64 + dt*16 + l16] = f2bf(oacc[dt][r] / rs[r]);
    }
  if (l16 == 0) {
#pragma unroll
    for (int r=0;r<4;++r) LB[obase + j0 + g*4 + r] = rm[r] + __logf(rs[r]);
  }
}

// ---------------- combine 3 branches via lse softmax -> attn bf16 (MPAD,768)
__global__ __launch_bounds__(256) void attn_combine_k(
   const unsigned short* __restrict__ o1, const float* __restrict__ l1,
   const unsigned short* __restrict__ o2, const float* __restrict__ l2,
   const unsigned short* __restrict__ o3, const float* __restrict__ l3,
   unsigned short* __restrict__ attn)
{
  int row = blockIdx.x; int t = threadIdx.x;
  unsigned short* arow = attn + (size_t)row*EMB;
  if (row >= MROWS) { arow[t]=0; arow[t+256]=0; arow[t+512]=0; return; }
  int b = row / SEQ, pos = row - (row/SEQ)*SEQ;
#pragma unroll
  for (int c0=0; c0<3; ++c0) {
    int cc = t + c0*256;
    int hd = cc >> 6, d = cc & 63;
    float L0,L1v,L2v,O0,O1v,O2v;
    {
      int seg = pos >> 9; int j = pos & 511;
      size_t base = ((size_t)(b*5 + seg)*NHEADS + hd)*512 + j;
      L0 = l1[base]; O0 = bf2f(o1[base*64 + d]);
    }
    if ((pos & 1) == (hd & 1)) {
      int seg = pos >> 10; int j = ((pos & 1023) - (hd&1)) >> 1;
      size_t base = ((size_t)(b*3 + seg)*NHEADS + hd)*512 + j;
      L1v = l2[base]; O1v = bf2f(o2[base*64 + d]);
    } else { L1v = NEGV; O1v = 0.f; }
    if ((pos & 3) == (hd & 3)) {
      int seg = pos >> 11; int j = ((pos & 2047) - (hd&3)) >> 2;
      size_t base = ((size_t)(b*2 + seg)*NHEADS + hd)*512 + j;
      L2v = l3[base]; O2v = bf2f(o3[base*64 + d]);
    } else { L2v = NEGV; O2v = 0.f; }
    float m = fmaxf(L0, fmaxf(L1v, L2v));
    float e0 = __expf(L0-m), e1 = __expf(L1v-m), e2 = __expf(L2v-m);
    float inv = 1.f/(e0+e1+e2);
    arow[cc] = f2bf((e0*O0+e1*O1v+e2*O2v)*inv);
  }
}

extern "C" void kernel_launch(void* const* d_in, const int* in_sizes, int n_in,
                              void* d_out, int out_size, void* d_ws, size_t ws_size,
                              hipStream_t stream) {
  const float* x       = (const float*)d_in[0];
  const float* conv_w  = (const float*)d_in[1];
  const float* conv_b  = (const float*)d_in[2];
  const float* cls     = (const float*)d_in[3];
  const float* pos_e   = (const float*)d_in[4];
  const float* ln1_g   = (const float*)d_in[5];
  const float* ln1_b   = (const float*)d_in[6];
  const float* wq      = (const float*)d_in[7];
  const float* bq      = (const float*)d_in[8];
  const float* wk      = (const float*)d_in[9];
  const float* bk      = (const float*)d_in[10];
  const float* wv      = (const float*)d_in[11];
  const float* bv      = (const float*)d_in[12];
  const float* wo      = (const float*)d_in[13];
  const float* bo      = (const float*)d_in[14];
  const float* ln2_g   = (const float*)d_in[15];
  const float* ln2_b   = (const float*)d_in[16];
  const float* w1      = (const float*)d_in[17];
  const float* b1      = (const float*)d_in[18];
  const float* w2      = (const float*)d_in[19];
  const float* b2      = (const float*)d_in[20];
  const float* nf_g    = (const float*)d_in[21];
  const float* nf_b    = (const float*)d_in[22];

  char* ws = (char*)d_ws;
  size_t off = 0;
  auto alloc = [&](size_t bytes)->char* {
    char* p = ws + off; off += (bytes + 255) & ~(size_t)255; return p;
  };
  unsigned short* wqkv_t = (unsigned short*)alloc((size_t)12*2304*768*2);
  unsigned short* wo_t   = (unsigned short*)alloc((size_t)12*768*768*2);
  unsigned short* w1_t   = (unsigned short*)alloc((size_t)12*3072*768*2);
  unsigned short* w2_t   = (unsigned short*)alloc((size_t)12*768*3072*2);
  unsigned short* cw_b   = (unsigned short*)alloc((size_t)768*4096*2);
  float* bqkv            = (float*)alloc((size_t)12*2304*4);
  unsigned short* Xp     = (unsigned short*)alloc((size_t)4096*4096*2);
  float* H               = (float*)alloc((size_t)MPAD*768*4);
  float* P               = (float*)alloc((size_t)4*MPAD*768*4);
  unsigned short* Y      = (unsigned short*)alloc((size_t)MPAD*768*2);
  unsigned short* QKV    = (unsigned short*)alloc((size_t)MPAD*2304*2);
  unsigned short* ATT    = (unsigned short*)alloc((size_t)MPAD*768*2);
  unsigned short* Y2     = (unsigned short*)alloc((size_t)MPAD*3072*2);
  unsigned short* O1 = (unsigned short*)alloc((size_t)2*5*12*512*64*2);
  unsigned short* O2 = (unsigned short*)alloc((size_t)2*3*12*512*64*2);
  unsigned short* O3 = (unsigned short*)alloc((size_t)2*2*12*512*64*2);
  float* L1 = (float*)alloc((size_t)2*5*12*512*4);
  float* L2 = (float*)alloc((size_t)2*3*12*512*4);
  float* L3 = (float*)alloc((size_t)2*2*12*512*4);
  const size_t PSTR = (size_t)MPAD*768;

  dim3 tb(32,8);
  wtr_k<<<dim3(24,24,12), tb, 0, stream>>>(wq, wqkv_t, 768, 768, 2304, 0);
  wtr_k<<<dim3(24,24,12), tb, 0, stream>>>(wk, wqkv_t, 768, 768, 2304, 768);
  wtr_k<<<dim3(24,24,12), tb, 0, stream>>>(wv, wqkv_t, 768, 768, 2304, 1536);
  wtr_k<<<dim3(24,24,12), tb, 0, stream>>>(wo, wo_t, 768, 768, 768, 0);
  wtr_k<<<dim3(24,96,12), tb, 0, stream>>>(w1, w1_t, 768, 3072, 3072, 0);
  wtr_k<<<dim3(96,24,12), tb, 0, stream>>>(w2, w2_t, 3072, 768, 768, 0);
  castconv_k<<<3072,256,0,stream>>>(conv_w, cw_b);
  biascat_k<<<108,256,0,stream>>>(bq,bk,bv,bqkv);
  patchify_k<<<16384,256,0,stream>>>(x, Xp);
  gemm_k<3,4><<<dim3(6,32,4),512,0,stream>>>(Xp, cw_b, conv_b, nullptr, P, 4096, 768, PSTR);
  assemble_k<<<MPAD,256,0,stream>>>(P, PSTR, cls, pos_e, H);

  for (int l=0;l<12;++l) {
    if (l==0) ln_k<<<MPAD,256,0,stream>>>(H, ln1_g, ln1_b, Y);
    else ln_red_k<2><<<MPAD,256,0,stream>>>(H, P, PSTR, ln1_g + l*768, ln1_b + l*768, Y);
    gemm_k<0,1><<<dim3(18,33),512,0,stream>>>(Y, wqkv_t + (size_t)l*2304*768, bqkv + l*2304, QKV, nullptr, 768, 2304, 0);
    attn_all_k<<<1920,256,0,stream>>>(QKV, O1,L1,O2,L2,O3,L3);
    attn_combine_k<<<MPAD,256,0,stream>>>(O1,L1,O2,L2,O3,L3, ATT);
    gemm_k<3,2><<<dim3(6,33,2),512,0,stream>>>(ATT, wo_t + (size_t)l*768*768, bo + l*768, nullptr, P, 768, 768, PSTR);
    ln_red_k<2><<<MPAD,256,0,stream>>>(H, P, PSTR, ln2_g + l*768, ln2_b + l*768, Y);
    gemm_k<1,1><<<dim3(24,33),512,0,stream>>>(Y, w1_t + (size_t)l*3072*768, b1 + l*3072, Y2, nullptr, 768, 3072, 0);
    gemm_k<3,2><<<dim3(6,33,2),512,0,stream>>>(Y2, w2_t + (size_t)l*768*3072, b2 + l*768, nullptr, P, 3072, 768, PSTR);
  }
  final_ln_red_k<2><<<2,256,0,stream>>>(H, P, PSTR, nf_g, nf_b, (float*)d_out);
}

// Round 13
// 2661.974 us; speedup vs baseline: 1.1259x; 1.0009x over previous
//
#include <hip/hip_runtime.h>
#include <math.h>

#define SEQ 2049
#define EMB 768
#define NHEADS 12
#define QKVW 2304
#define MROWS 4098
#define MPAD 4224
#define NEGV -1000000000.0f

typedef short bs8 __attribute__((ext_vector_type(8)));
typedef float f4 __attribute__((ext_vector_type(4)));

__device__ __forceinline__ unsigned short f2bf(float f){
  union { float f; unsigned u; } x; x.f = f;
  unsigned r = x.u + 0x7fffu + ((x.u >> 16) & 1u);
  return (unsigned short)(r >> 16);
}
__device__ __forceinline__ unsigned short f2bf_fast(float f){
  union { float f; unsigned u; } x; x.f = f;
  return (unsigned short)((x.u + 0x8000u) >> 16);
}
__device__ __forceinline__ float bf2f(unsigned short u){
  union { unsigned u; float f; } x; x.u = ((unsigned)u) << 16; return x.f;
}

__device__ __forceinline__ float gelu_f(float x){
  float ax = fabsf(x)*0.70710678f;
  float t = 1.f/(1.f + 0.3275911f*ax);
  float p = t*(0.254829592f + t*(-0.284496736f + t*(1.421413741f
            + t*(-1.453152027f + t*1.061405429f))));
  float erfv = 1.f - p*__expf(-ax*ax);
  float s = (x >= 0.f) ? erfv : -erfv;
  return 0.5f*x*(1.f + s);
}

__device__ __forceinline__ void gl_lds16(const void* g, void* l){
  __builtin_amdgcn_global_load_lds((const __attribute__((address_space(1))) void*)g,
                                   (__attribute__((address_space(3))) void*)l, 16, 0, 0);
}

// ---------------- weight transpose fp32 (L,K,N) -> bf16 dst[(l*LD+NOFF+n)*K+k]
__global__ void wtr_k(const float* __restrict__ src, unsigned short* __restrict__ dst,
                      int K, int N, int LD, int NOFF)
{
  __shared__ float tile[32][33];
  int k0 = blockIdx.x*32, n0 = blockIdx.y*32, z = blockIdx.z;
  int tx = threadIdx.x, ty = threadIdx.y;
  const float* s = src + (size_t)z*K*N;
#pragma unroll
  for (int i=0;i<4;++i)
    tile[ty*4+i][tx] = s[(size_t)(k0+ty*4+i)*N + n0+tx];
  __syncthreads();
  unsigned short* dz = dst + ((size_t)z*LD + NOFF)*K;
#pragma unroll
  for (int i=0;i<4;++i)
    dz[(size_t)(n0+ty*4+i)*K + k0+tx] = f2bf(tile[tx][ty*4+i]);
}

__global__ void castconv_k(const float* __restrict__ src, unsigned short* __restrict__ dst){
  size_t i = ((size_t)blockIdx.x*256 + threadIdx.x)*4;
  float4 f = *(const float4*)(src+i);
  dst[i+0]=f2bf(f.x); dst[i+1]=f2bf(f.y); dst[i+2]=f2bf(f.z); dst[i+3]=f2bf(f.w);
}

__global__ void biascat_k(const float* __restrict__ bq, const float* __restrict__ bk,
                          const float* __restrict__ bv, float* __restrict__ dst){
  int i = blockIdx.x*256+threadIdx.x;
  int l = i/QKVW, c = i%QKVW;
  float v = (c<768) ? bq[l*768+c] : (c<1536 ? bk[l*768+c-768] : bv[l*768+c-1536]);
  dst[i] = v;
}

// ---------------- patch extraction
__global__ void patchify_k(const float* __restrict__ x, unsigned short* __restrict__ Xp)
{
  size_t gid = (size_t)blockIdx.x*256 + threadIdx.x;
  size_t oi = gid*4;
  int row = (int)(oi >> 12);
  int c = (int)(oi & 4095);
  int b = row >> 11; int p = row & 2047;
  int pd = p >> 8, ph = (p>>4)&15, pw = p&15;
  int pz = c >> 8, py = (c>>4)&15, px = c&15;
  size_t src = (((size_t)(b*128 + pd*16+pz)*256) + (size_t)(ph*16+py))*256 + (size_t)(pw*16+px);
  float4 f = *(const float4*)(x+src);
  Xp[oi+0]=f2bf(f.x); Xp[oi+1]=f2bf(f.y); Xp[oi+2]=f2bf(f.z); Xp[oi+3]=f2bf(f.w);
}

// ---------------- assemble h = [cls; sum4(P)] + pos, zero pads
__global__ void assemble_k(const float* __restrict__ P, size_t pstride,
                           const float* __restrict__ cls,
                           const float* __restrict__ pos_e, float* __restrict__ H)
{
  int row = blockIdx.x; int t = threadIdx.x;
  float* hr = H + (size_t)row*EMB;
  if (row >= MROWS) { hr[t]=0.f; hr[t+256]=0.f; hr[t+512]=0.f; return; }
  int b = row / SEQ; int pos = row - b*SEQ;
#pragma unroll
  for (int c0=0;c0<3;++c0) {
    int c = t + c0*256;
    float v;
    if (pos==0) v = cls[c];
    else {
      size_t idx = ((size_t)(b*2048 + pos-1))*EMB + c;
      v = P[idx] + P[pstride+idx] + P[2*pstride+idx] + P[3*pstride+idx];
    }
    hr[c] = v + pos_e[(size_t)pos*EMB + c];
  }
}

// ---------------- layernorm row -> bf16
__global__ __launch_bounds__(256) void ln_k(const float* __restrict__ H,
    const float* __restrict__ gam, const float* __restrict__ bet,
    unsigned short* __restrict__ Y)
{
  int row = blockIdx.x, t = threadIdx.x;
  const float* hr = H + (size_t)row*EMB;
  float v0 = hr[t], v1 = hr[t+256], v2 = hr[t+512];
  float s = v0+v1+v2;
#pragma unroll
  for (int off=32; off>=1; off>>=1) s += __shfl_down(s, off);
  __shared__ float r1[4], r2[4];
  if ((t&63)==0) r1[t>>6] = s;
  __syncthreads();
  float mean = (r1[0]+r1[1]+r1[2]+r1[3]) * (1.f/768.f);
  float d0=v0-mean, d1=v1-mean, d2=v2-mean;
  float q = d0*d0+d1*d1+d2*d2;
#pragma unroll
  for (int off=32; off>=1; off>>=1) q += __shfl_down(q, off);
  if ((t&63)==0) r2[t>>6] = q;
  __syncthreads();
  float rstd = rsqrtf((r2[0]+r2[1]+r2[2]+r2[3])*(1.f/768.f) + 1e-5f);
  unsigned short* yr = Y + (size_t)row*EMB;
  yr[t]     = f2bf(d0*rstd*gam[t]     + bet[t]);
  yr[t+256] = f2bf(d1*rstd*gam[t+256] + bet[t+256]);
  yr[t+512] = f2bf(d2*rstd*gam[t+512] + bet[t+512]);
}

// ---------------- fused: H += sum_{s<S} P[s]; Y = LN(H)
template<int S>
__global__ __launch_bounds__(256) void ln_red_k(float* __restrict__ H,
    const float* __restrict__ P, size_t pstride,
    const float* __restrict__ gam, const float* __restrict__ bet,
    unsigned short* __restrict__ Y)
{
  int row = blockIdx.x, t = threadIdx.x;
  size_t base = (size_t)row*EMB;
  float v[3];
#pragma unroll
  for (int c0=0;c0<3;++c0) {
    size_t idx = base + t + c0*256;
    float h = H[idx];
#pragma unroll
    for (int s=0;s<S;++s) h += P[(size_t)s*pstride + idx];
    H[idx] = h; v[c0] = h;
  }
  float s = v[0]+v[1]+v[2];
#pragma unroll
  for (int off=32; off>=1; off>>=1) s += __shfl_down(s, off);
  __shared__ float r1[4], r2[4];
  if ((t&63)==0) r1[t>>6] = s;
  __syncthreads();
  float mean = (r1[0]+r1[1]+r1[2]+r1[3]) * (1.f/768.f);
  float d0=v[0]-mean, d1=v[1]-mean, d2=v[2]-mean;
  float q = d0*d0+d1*d1+d2*d2;
#pragma unroll
  for (int off=32; off>=1; off>>=1) q += __shfl_down(q, off);
  if ((t&63)==0) r2[t>>6] = q;
  __syncthreads();
  float rstd = rsqrtf((r2[0]+r2[1]+r2[2]+r2[3])*(1.f/768.f) + 1e-5f);
  unsigned short* yr = Y + base;
  yr[t]     = f2bf(d0*rstd*gam[t]     + bet[t]);
  yr[t+256] = f2bf(d1*rstd*gam[t+256] + bet[t+256]);
  yr[t+512] = f2bf(d2*rstd*gam[t+512] + bet[t+512]);
}

// ---------------- final layernorm on cls rows -> fp32 out
template<int S>
__global__ __launch_bounds__(256) void final_ln_red_k(const float* __restrict__ H,
   const float* __restrict__ P, size_t pstride,
   const float* __restrict__ gam, const float* __restrict__ bet, float* __restrict__ out)
{
  int b = blockIdx.x, t = threadIdx.x;
  size_t base = (size_t)(b*SEQ)*EMB;
  float v[3];
#pragma unroll
  for (int c0=0;c0<3;++c0) {
    size_t idx = base + t + c0*256;
    float h = H[idx];
#pragma unroll
    for (int s=0;s<S;++s) h += P[(size_t)s*pstride + idx];
    v[c0] = h;
  }
  float s = v[0]+v[1]+v[2];
#pragma unroll
  for (int off=32; off>=1; off>>=1) s += __shfl_down(s, off);
  __shared__ float r1[4], r2[4];
  if ((t&63)==0) r1[t>>6] = s;
  __syncthreads();
  float mean = (r1[0]+r1[1]+r1[2]+r1[3]) * (1.f/768.f);
  float d0=v[0]-mean, d1=v[1]-mean, d2=v[2]-mean;
  float q = d0*d0+d1*d1+d2*d2;
#pragma unroll
  for (int off=32; off>=1; off>>=1) q += __shfl_down(q, off);
  if ((t&63)==0) r2[t>>6] = q;
  __syncthreads();
  float rstd = rsqrtf((r2[0]+r2[1]+r2[2]+r2[3])*(1.f/768.f) + 1e-5f);
  out[b*EMB + t]     = d0*rstd*gam[t]     + bet[t];
  out[b*EMB + t+256] = d1*rstd*gam[t+256] + bet[t+256];
  out[b*EMB + t+512] = d2*rstd*gam[t+512] + bet[t+512];
}

// ---------------- GEMM: 128x128 tile, 512 threads / 8 waves (r12 config, passed)
template<int MODE, int NSPLIT>
__global__ __launch_bounds__(512) void gemm_k(
    const unsigned short* __restrict__ A,
    const unsigned short* __restrict__ Bt,
    const float* __restrict__ bias,
    unsigned short* __restrict__ Cb,
    float* __restrict__ Cf,
    int K, int ldc, size_t splitStride)
{
  __shared__ __attribute__((aligned(16))) unsigned short lA[3][128*32];
  __shared__ __attribute__((aligned(16))) unsigned short lB[3][128*32];
  const int tid = threadIdx.x;
  const int w = tid>>6, lane = tid&63, g = lane>>4, l16 = lane&15;
  const int lr = lane>>2;
  const int lcs = (((lane&3) ^ ((lane>>3)&3)))*8;
  const int swz = ((g ^ ((l16>>1)&3)))*8;
  const int nwg = gridDim.x*gridDim.y;
  const int id = blockIdx.y*gridDim.x + blockIdx.x;
  const int q = nwg>>3, r = nwg&7, xc = id&7, si = id>>3;
  const int nid = (xc<r ? xc*(q+1) : r*(q+1)+(xc-r)*q) + si;
  const int tm = nid / gridDim.x;
  const int tn = nid - tm*gridDim.x;
  const int kchunk = K / NSPLIT;
  const int kofs = (NSPLIT>1) ? blockIdx.z * kchunk : 0;
  const unsigned short* Ab = A + (size_t)tm*128*K + kofs;
  const unsigned short* Bb = Bt + (size_t)tn*128*K + kofs;
  const int wm = (w>>2)*64, wn = (w&3)*32;
  f4 acc[4][2] = {};
  const int nkt = kchunk>>5;

  auto STAGE = [&](int buf, int kt){
    const size_t ko = (size_t)(kt*32 + lcs);
    gl_lds16(Ab + (size_t)(w*16 + lr)*K + ko, ((char*)lA[buf]) + w*1024);
    gl_lds16(Bb + (size_t)(w*16 + lr)*K + ko, ((char*)lB[buf]) + w*1024);
  };

  STAGE(0, 0);
  STAGE(1, 1);
  for (int kt=0; kt<nkt; ++kt) {
    const int cur = kt % 3;
    if (kt+2 < nkt) {
      STAGE((kt+2)%3, kt+2);
      asm volatile("s_waitcnt vmcnt(4)" ::: "memory");
    } else if (kt+1 < nkt) {
      asm volatile("s_waitcnt vmcnt(2)" ::: "memory");
    } else {
      asm volatile("s_waitcnt vmcnt(0)" ::: "memory");
    }
    __builtin_amdgcn_sched_barrier(0);
    __builtin_amdgcn_s_barrier();
    bs8 af[4], bf[2];
#pragma unroll
    for (int mi=0;mi<4;++mi) af[mi] = *(const bs8*)(lA[cur] + (wm+mi*16+l16)*32 + swz);
#pragma unroll
    for (int ni=0;ni<2;++ni) bf[ni] = *(const bs8*)(lB[cur] + (wn+ni*16+l16)*32 + swz);
    asm volatile("s_waitcnt lgkmcnt(0)" ::: "memory");
    __builtin_amdgcn_sched_barrier(0);
    __builtin_amdgcn_s_barrier();
#pragma unroll
    for (int mi=0;mi<4;++mi)
#pragma unroll
      for (int ni=0;ni<2;++ni)
        acc[mi][ni] = __builtin_amdgcn_mfma_f32_16x16x32_bf16(af[mi], bf[ni], acc[mi][ni], 0,0,0);
  }
  const float bscale = (NSPLIT==1 || blockIdx.z==0) ? 1.f : 0.f;
#pragma unroll
  for (int mi=0;mi<4;++mi)
#pragma unroll
    for (int ni=0;ni<2;++ni) {
      int col = tn*128 + wn + ni*16 + l16;
      float bv = bias[col]*bscale;
#pragma unroll
      for (int r0=0;r0<4;++r0) {
        int row = tm*128 + wm + mi*16 + g*4 + r0;
        float val = acc[mi][ni][r0] + bv;
        if (MODE==1) val = gelu_f(val);
        if (MODE<=1) Cb[(size_t)row*ldc + col] = f2bf(val);
        else Cf[(size_t)blockIdx.z*splitStride + (size_t)row*ldc + col] = val;
      }
    }
}

// ---------------- fused dilated attention: Pl alias + granule swizzle,
// scaled-max softmax (fma into exp, no pre-scale pass).
__global__ __launch_bounds__(256) void attn_all_k(
    const unsigned short* __restrict__ qkv,
    unsigned short* __restrict__ O1, float* __restrict__ L1,
    unsigned short* __restrict__ O2, float* __restrict__ L2,
    unsigned short* __restrict__ O3, float* __restrict__ L3)
{
  __shared__ __attribute__((aligned(16))) unsigned short lsm[128*72 + 64*136];
  unsigned short* lK  = lsm;
  unsigned short* lVt = lsm + 128*72;
  const int tid = threadIdx.x;
  const int w = tid>>6, lane = tid&63, g = lane>>4, l16 = lane&15;

  int id = (blockIdx.x & 7)*240 + (blockIdx.x >> 3);
  int R, WSZ, NSEG; unsigned short* OB; float* LB;
  if (id < 960)       { R=1; WSZ=512;  NSEG=5; OB=O1; LB=L1; }
  else if (id < 1536) { id -= 960;  R=2; WSZ=1024; NSEG=3; OB=O2; LB=L2; }
  else                { id -= 1536; R=4; WSZ=2048; NSEG=2; OB=O3; LB=L3; }
  const int qt = id & 7; int rest = id >> 3;
  const int seg = rest % NSEG; const int bh = rest / NSEG;
  const int b = bh / NHEADS, hd = bh % NHEADS;
  const int hr = hd % R;
  const int kbase = seg*WSZ + hr;
  bs8 z = {0,0,0,0,0,0,0,0};

  if (kbase + qt*64*R >= SEQ) {
    size_t ob2 = ((size_t)(b*NSEG + seg)*NHEADS + hd)*512 + qt*64;
    int row = tid>>2, cb = (tid&3)*16;
    *(bs8*)(&OB[(ob2 + row)*64 + cb])     = z;
    *(bs8*)(&OB[(ob2 + row)*64 + cb + 8]) = z;
    if (tid < 64) LB[ob2 + tid] = NEGV;
    return;
  }
  int nvk = (SEQ - 1 - kbase)/R + 1; if (nvk > 512) nvk = 512;
  const int nck = (nvk + 127) >> 7;

  const int j0 = qt*64 + w*16;
  const unsigned short* qkvb = qkv + (size_t)b*SEQ*QKVW;

  bs8 qf0 = z, qf1 = z;
  {
    int qpos = kbase + (j0 + l16)*R;
    if (qpos < SEQ) {
      const unsigned short* qrow = qkvb + (size_t)qpos*QKVW + hd*64 + g*8;
      qf0 = *(const bs8*)(qrow);
      qf1 = *(const bs8*)(qrow + 32);
    }
  }

  const int dbK = tid&7, kkKb = tid>>3;
  const int kkV = tid&127, dbV0 = tid>>7;
  const unsigned short* pK = qkvb + (size_t)(kbase + kkKb*R)*QKVW + EMB + hd*64 + dbK*8;
  const unsigned short* pV = qkvb + (size_t)(kbase + kkV*R)*QKVW + 1536 + hd*64 + dbV0*8;
  const size_t stepIt = (size_t)32*R*QKVW;
  const size_t stepC  = (size_t)128*R*QKVW;
  int ci = 0;
  bs8 kreg[4], vreg[4];
  auto ISSUE = [&](){
    const bool full = (kbase + (ci*128 + 127)*R) < SEQ;
    if (full) {
#pragma unroll
      for (int it=0; it<4; ++it) kreg[it] = *(const bs8*)(pK + (size_t)it*stepIt);
#pragma unroll
      for (int it=0; it<4; ++it) vreg[it] = *(const bs8*)(pV + it*16);
    } else {
      const int cofs = ci*128*R;
#pragma unroll
      for (int it=0; it<4; ++it)
        kreg[it] = (kbase + (kkKb + it*32)*R + cofs < SEQ)
                   ? *(const bs8*)(pK + (size_t)it*stepIt) : z;
      const bool vv = (kbase + kkV*R + cofs) < SEQ;
#pragma unroll
      for (int it=0; it<4; ++it) vreg[it] = vv ? *(const bs8*)(pV + it*16) : z;
    }
    pK += stepC; pV += stepC; ++ci;
  };

  float rm[4], rs[4];
  f4 oacc[4] = {};
#pragma unroll
  for (int r=0;r<4;++r) { rm[r] = NEGV; rs[r] = 0.f; }

  ISSUE();
  for (int c=0; c<nck; ++c) {
    __syncthreads();                // all waves done with PV(c-1): lK(Pl) & lVt free
#pragma unroll
    for (int it=0; it<4; ++it) {
      *(bs8*)(lK + (kkKb + it*32)*72 + dbK*8) = kreg[it];
#pragma unroll
      for (int ii=0; ii<8; ++ii) lVt[((dbV0+it*2)*8+ii)*136 + kkV] = (unsigned short)vreg[it][ii];
    }
    __syncthreads();                // chunk c staged, visible
    if (c+1 < nck) ISSUE();         // next chunk's loads overlap compute

    const bool fullc = (kbase + (c*128 + 127)*R) < SEQ;
    f4 sc[8];                       // RAW scores (unscaled)
    __builtin_amdgcn_s_setprio(1);
#pragma unroll
    for (int kt=0; kt<8; ++kt) {
      int key = kt*16 + l16;
      bs8 kf0 = *(const bs8*)(lK + key*72 + g*8);
      bs8 kf1 = *(const bs8*)(lK + key*72 + 32 + g*8);
      f4 acc = {0.f,0.f,0.f,0.f};
      acc = __builtin_amdgcn_mfma_f32_16x16x32_bf16(qf0, kf0, acc, 0,0,0);
      acc = __builtin_amdgcn_mfma_f32_16x16x32_bf16(qf1, kf1, acc, 0,0,0);
      sc[kt] = acc;
    }
    __builtin_amdgcn_s_setprio(0);
    __syncthreads();                // all waves done reading lK -> Pl may overwrite it
    if (!fullc) {
#pragma unroll
      for (int kt=0; kt<8; ++kt) {
        bool kvld = (kbase + (c*128 + kt*16 + l16)*R) < SEQ;
#pragma unroll
        for (int r=0;r<4;++r) sc[kt][r] = kvld ? sc[kt][r] : NEGV;
      }
    }
    float scl[4];
#pragma unroll
    for (int r=0;r<4;++r) {
      float mx = sc[0][r];
#pragma unroll
      for (int kt=1;kt<8;++kt) mx = fmaxf(mx, sc[kt][r]);
      mx = fmaxf(mx, __shfl_xor(mx, 1));
      mx = fmaxf(mx, __shfl_xor(mx, 2));
      mx = fmaxf(mx, __shfl_xor(mx, 4));
      mx = fmaxf(mx, __shfl_xor(mx, 8));
      float mn = fmaxf(rm[r], mx*0.125f);   // rm tracked in scaled units
      scl[r] = __expf(rm[r] - mn);
      rm[r] = mn;
    }
#pragma unroll
    for (int r=0;r<4;++r) {
      float sm = 0.f;
      float nrm = -rm[r];
#pragma unroll
      for (int kt=0;kt<8;++kt) {
        float p = __expf(__builtin_fmaf(sc[kt][r], 0.125f, nrm));
        sc[kt][r] = p; sm += p;
      }
      rs[r] = rs[r]*scl[r] + sm;
    }
    if (scl[0]<1.f || scl[1]<1.f || scl[2]<1.f || scl[3]<1.f) {
#pragma unroll
      for (int dt=0; dt<4; ++dt)
#pragma unroll
        for (int r=0;r<4;++r) oacc[dt][r] *= scl[r];
    }
    // Pl aliases lK, stride 136, 16B-granule swizzled by row bit 3:
    // write (row=g*4+r, col=kt*16+l16): granule = (kt*2 + (l16>>3)) ^ ((row>>3)&1)
    unsigned short* Plw = lK + w*16*136;
#pragma unroll
    for (int kt=0;kt<8;++kt)
#pragma unroll
      for (int r=0;r<4;++r) {
        int row = g*4+r;
        int gr = (kt*2 + (l16>>3)) ^ ((row>>3)&1);
        Plw[row*136 + gr*8 + (l16&7)] = f2bf_fast(sc[kt][r]);
      }
    __builtin_amdgcn_s_setprio(1);
#pragma unroll
    for (int ks=0; ks<4; ++ks) {
      int grp = ((ks*4+g) ^ ((l16>>3)&1))*8;
      bs8 pa = *(const bs8*)(Plw + l16*136 + grp);
#pragma unroll
      for (int dt=0; dt<4; ++dt) {
        bs8 vb = *(const bs8*)(lVt + (dt*16+l16)*136 + ks*32 + g*8);
        oacc[dt] = __builtin_amdgcn_mfma_f32_16x16x32_bf16(pa, vb, oacc[dt], 0,0,0);
      }
    }
    __builtin_amdgcn_s_setprio(0);
  }

#pragma unroll
  for (int r=0;r<4;++r) {
    float s = rs[r];
    s += __shfl_xor(s, 1); s += __shfl_xor(s, 2);
    s += __shfl_xor(s, 4); s += __shfl_xor(s, 8);
    rs[r] = s;
  }

  size_t obase = ((size_t)(b*NSEG + seg)*NHEADS + hd)*512;
#pragma unroll
  for (int dt=0; dt<4; ++dt)
#pragma unroll
    for (int r=0;r<4;++r) {
      int j = j0 + g*4 + r;
      OB[(obase + j)*64 + dt*16 + l16] = f2bf(oacc[dt][r] / rs[r]);
    }
  if (l16 == 0) {
#pragma unroll
    for (int r=0;r<4;++r) LB[obase + j0 + g*4 + r] = rm[r] + __logf(rs[r]);
  }
}

// ---------------- combine 3 branches via lse softmax -> attn bf16 (MPAD,768)
__global__ __launch_bounds__(256) void attn_combine_k(
   const unsigned short* __restrict__ o1, const float* __restrict__ l1,
   const unsigned short* __restrict__ o2, const float* __restrict__ l2,
   const unsigned short* __restrict__ o3, const float* __restrict__ l3,
   unsigned short* __restrict__ attn)
{
  int row = blockIdx.x; int t = threadIdx.x;
  unsigned short* arow = attn + (size_t)row*EMB;
  if (row >= MROWS) { arow[t]=0; arow[t+256]=0; arow[t+512]=0; return; }
  int b = row / SEQ, pos = row - (row/SEQ)*SEQ;
#pragma unroll
  for (int c0=0; c0<3; ++c0) {
    int cc = t + c0*256;
    int hd = cc >> 6, d = cc & 63;
    float L0,L1v,L2v,O0,O1v,O2v;
    {
      int seg = pos >> 9; int j = pos & 511;
      size_t base = ((size_t)(b*5 + seg)*NHEADS + hd)*512 + j;
      L0 = l1[base]; O0 = bf2f(o1[base*64 + d]);
    }
    if ((pos & 1) == (hd & 1)) {
      int seg = pos >> 10; int j = ((pos & 1023) - (hd&1)) >> 1;
      size_t base = ((size_t)(b*3 + seg)*NHEADS + hd)*512 + j;
      L1v = l2[base]; O1v = bf2f(o2[base*64 + d]);
    } else { L1v = NEGV; O1v = 0.f; }
    if ((pos & 3) == (hd & 3)) {
      int seg = pos >> 11; int j = ((pos & 2047) - (hd&3)) >> 2;
      size_t base = ((size_t)(b*2 + seg)*NHEADS + hd)*512 + j;
      L2v = l3[base]; O2v = bf2f(o3[base*64 + d]);
    } else { L2v = NEGV; O2v = 0.f; }
    float m = fmaxf(L0, fmaxf(L1v, L2v));
    float e0 = __expf(L0-m), e1 = __expf(L1v-m), e2 = __expf(L2v-m);
    float inv = 1.f/(e0+e1+e2);
    arow[cc] = f2bf((e0*O0+e1*O1v+e2*O2v)*inv);
  }
}

extern "C" void kernel_launch(void* const* d_in, const int* in_sizes, int n_in,
                              void* d_out, int out_size, void* d_ws, size_t ws_size,
                              hipStream_t stream) {
  const float* x       = (const float*)d_in[0];
  const float* conv_w  = (const float*)d_in[1];
  const float* conv_b  = (const float*)d_in[2];
  const float* cls     = (const float*)d_in[3];
  const float* pos_e   = (const float*)d_in[4];
  const float* ln1_g   = (const float*)d_in[5];
  const float* ln1_b   = (const float*)d_in[6];
  const float* wq      = (const float*)d_in[7];
  const float* bq      = (const float*)d_in[8];
  const float* wk      = (const float*)d_in[9];
  const float* bk      = (const float*)d_in[10];
  const float* wv      = (const float*)d_in[11];
  const float* bv      = (const float*)d_in[12];
  const float* wo      = (const float*)d_in[13];
  const float* bo      = (const float*)d_in[14];
  const float* ln2_g   = (const float*)d_in[15];
  const float* ln2_b   = (const float*)d_in[16];
  const float* w1      = (const float*)d_in[17];
  const float* b1      = (const float*)d_in[18];
  const float* w2      = (const float*)d_in[19];
  const float* b2      = (const float*)d_in[20];
  const float* nf_g    = (const float*)d_in[21];
  const float* nf_b    = (const float*)d_in[22];

  char* ws = (char*)d_ws;
  size_t off = 0;
  auto alloc = [&](size_t bytes)->char* {
    char* p = ws + off; off += (bytes + 255) & ~(size_t)255; return p;
  };
  unsigned short* wqkv_t = (unsigned short*)alloc((size_t)12*2304*768*2);
  unsigned short* wo_t   = (unsigned short*)alloc((size_t)12*768*768*2);
  unsigned short* w1_t   = (unsigned short*)alloc((size_t)12*3072*768*2);
  unsigned short* w2_t   = (unsigned short*)alloc((size_t)12*768*3072*2);
  unsigned short* cw_b   = (unsigned short*)alloc((size_t)768*4096*2);
  float* bqkv            = (float*)alloc((size_t)12*2304*4);
  unsigned short* Xp     = (unsigned short*)alloc((size_t)4096*4096*2);
  float* H               = (float*)alloc((size_t)MPAD*768*4);
  float* P               = (float*)alloc((size_t)4*MPAD*768*4);
  unsigned short* Y      = (unsigned short*)alloc((size_t)MPAD*768*2);
  unsigned short* QKV    = (unsigned short*)alloc((size_t)MPAD*2304*2);
  unsigned short* ATT    = (unsigned short*)alloc((size_t)MPAD*768*2);
  unsigned short* Y2     = (unsigned short*)alloc((size_t)MPAD*3072*2);
  unsigned short* O1 = (unsigned short*)alloc((size_t)2*5*12*512*64*2);
  unsigned short* O2 = (unsigned short*)alloc((size_t)2*3*12*512*64*2);
  unsigned short* O3 = (unsigned short*)alloc((size_t)2*2*12*512*64*2);
  float* L1 = (float*)alloc((size_t)2*5*12*512*4);
  float* L2 = (float*)alloc((size_t)2*3*12*512*4);
  float* L3 = (float*)alloc((size_t)2*2*12*512*4);
  const size_t PSTR = (size_t)MPAD*768;

  dim3 tb(32,8);
  wtr_k<<<dim3(24,24,12), tb, 0, stream>>>(wq, wqkv_t, 768, 768, 2304, 0);
  wtr_k<<<dim3(24,24,12), tb, 0, stream>>>(wk, wqkv_t, 768, 768, 2304, 768);
  wtr_k<<<dim3(24,24,12), tb, 0, stream>>>(wv, wqkv_t, 768, 768, 2304, 1536);
  wtr_k<<<dim3(24,24,12), tb, 0, stream>>>(wo, wo_t, 768, 768, 768, 0);
  wtr_k<<<dim3(24,96,12), tb, 0, stream>>>(w1, w1_t, 768, 3072, 3072, 0);
  wtr_k<<<dim3(96,24,12), tb, 0, stream>>>(w2, w2_t, 3072, 768, 768, 0);
  castconv_k<<<3072,256,0,stream>>>(conv_w, cw_b);
  biascat_k<<<108,256,0,stream>>>(bq,bk,bv,bqkv);
  patchify_k<<<16384,256,0,stream>>>(x, Xp);
  gemm_k<3,4><<<dim3(6,32,4),512,0,stream>>>(Xp, cw_b, conv_b, nullptr, P, 4096, 768, PSTR);
  assemble_k<<<MPAD,256,0,stream>>>(P, PSTR, cls, pos_e, H);

  for (int l=0;l<12;++l) {
    if (l==0) ln_k<<<MPAD,256,0,stream>>>(H, ln1_g, ln1_b, Y);
    else ln_red_k<2><<<MPAD,256,0,stream>>>(H, P, PSTR, ln1_g + l*768, ln1_b + l*768, Y);
    gemm_k<0,1><<<dim3(18,33),512,0,stream>>>(Y, wqkv_t + (size_t)l*2304*768, bqkv + l*2304, QKV, nullptr, 768, 2304, 0);
    attn_all_k<<<1920,256,0,stream>>>(QKV, O1,L1,O2,L2,O3,L3);
    attn_combine_k<<<MPAD,256,0,stream>>>(O1,L1,O2,L2,O3,L3, ATT);
    gemm_k<3,2><<<dim3(6,33,2),512,0,stream>>>(ATT, wo_t + (size_t)l*768*768, bo + l*768, nullptr, P, 768, 768, PSTR);
    ln_red_k<2><<<MPAD,256,0,stream>>>(H, P, PSTR, ln2_g + l*768, ln2_b + l*768, Y);
    gemm_k<1,1><<<dim3(24,33),512,0,stream>>>(Y, w1_t + (size_t)l*3072*768, b1 + l*3072, Y2, nullptr, 768, 3072, 0);
    gemm_k<3,2><<<dim3(6,33,2),512,0,stream>>>(Y2, w2_t + (size_t)l*768*3072, b2 + l*768, nullptr, P, 3072, 768, PSTR);
  }
  final_ln_red_k<2><<<2,256,0,stream>>>(H, P, PSTR, nf_g, nf_b, (float*)d_out);
}

// Round 14
// 2653.880 us; speedup vs baseline: 1.1293x; 1.0031x over previous
//
#include <hip/hip_runtime.h>
#include <math.h>

#define SEQ 2049
#define EMB 768
#define NHEADS 12
#define QKVW 2304
#define MROWS 4098
#define MPAD 4224
#define NEGV -1000000000.0f

typedef short bs8 __attribute__((ext_vector_type(8)));
typedef float f4 __attribute__((ext_vector_type(4)));

__device__ __forceinline__ unsigned short f2bf(float f){
  union { float f; unsigned u; } x; x.f = f;
  unsigned r = x.u + 0x7fffu + ((x.u >> 16) & 1u);
  return (unsigned short)(r >> 16);
}
__device__ __forceinline__ unsigned short f2bf_fast(float f){
  union { float f; unsigned u; } x; x.f = f;
  return (unsigned short)((x.u + 0x8000u) >> 16);
}
__device__ __forceinline__ float bf2f(unsigned short u){
  union { unsigned u; float f; } x; x.u = ((unsigned)u) << 16; return x.f;
}

__device__ __forceinline__ float gelu_f(float x){
  float ax = fabsf(x)*0.70710678f;
  float t = 1.f/(1.f + 0.3275911f*ax);
  float p = t*(0.254829592f + t*(-0.284496736f + t*(1.421413741f
            + t*(-1.453152027f + t*1.061405429f))));
  float erfv = 1.f - p*__expf(-ax*ax);
  float s = (x >= 0.f) ? erfv : -erfv;
  return 0.5f*x*(1.f + s);
}

__device__ __forceinline__ void gl_lds16(const void* g, void* l){
  __builtin_amdgcn_global_load_lds((const __attribute__((address_space(1))) void*)g,
                                   (__attribute__((address_space(3))) void*)l, 16, 0, 0);
}

// ---------------- weight transpose fp32 (L,K,N) -> bf16 dst[(l*LD+NOFF+n)*K+k]
__global__ void wtr_k(const float* __restrict__ src, unsigned short* __restrict__ dst,
                      int K, int N, int LD, int NOFF)
{
  __shared__ float tile[32][33];
  int k0 = blockIdx.x*32, n0 = blockIdx.y*32, z = blockIdx.z;
  int tx = threadIdx.x, ty = threadIdx.y;
  const float* s = src + (size_t)z*K*N;
#pragma unroll
  for (int i=0;i<4;++i)
    tile[ty*4+i][tx] = s[(size_t)(k0+ty*4+i)*N + n0+tx];
  __syncthreads();
  unsigned short* dz = dst + ((size_t)z*LD + NOFF)*K;
#pragma unroll
  for (int i=0;i<4;++i)
    dz[(size_t)(n0+ty*4+i)*K + k0+tx] = f2bf(tile[tx][ty*4+i]);
}

__global__ void castconv_k(const float* __restrict__ src, unsigned short* __restrict__ dst){
  size_t i = ((size_t)blockIdx.x*256 + threadIdx.x)*4;
  float4 f = *(const float4*)(src+i);
  dst[i+0]=f2bf(f.x); dst[i+1]=f2bf(f.y); dst[i+2]=f2bf(f.z); dst[i+3]=f2bf(f.w);
}

__global__ void biascat_k(const float* __restrict__ bq, const float* __restrict__ bk,
                          const float* __restrict__ bv, float* __restrict__ dst){
  int i = blockIdx.x*256+threadIdx.x;
  int l = i/QKVW, c = i%QKVW;
  float v = (c<768) ? bq[l*768+c] : (c<1536 ? bk[l*768+c-768] : bv[l*768+c-1536]);
  dst[i] = v;
}

// ---------------- patch extraction
__global__ void patchify_k(const float* __restrict__ x, unsigned short* __restrict__ Xp)
{
  size_t gid = (size_t)blockIdx.x*256 + threadIdx.x;
  size_t oi = gid*4;
  int row = (int)(oi >> 12);
  int c = (int)(oi & 4095);
  int b = row >> 11; int p = row & 2047;
  int pd = p >> 8, ph = (p>>4)&15, pw = p&15;
  int pz = c >> 8, py = (c>>4)&15, px = c&15;
  size_t src = (((size_t)(b*128 + pd*16+pz)*256) + (size_t)(ph*16+py))*256 + (size_t)(pw*16+px);
  float4 f = *(const float4*)(x+src);
  Xp[oi+0]=f2bf(f.x); Xp[oi+1]=f2bf(f.y); Xp[oi+2]=f2bf(f.z); Xp[oi+3]=f2bf(f.w);
}

// ---------------- assemble h = [cls; sum4(P)] + pos, zero pads
__global__ void assemble_k(const float* __restrict__ P, size_t pstride,
                           const float* __restrict__ cls,
                           const float* __restrict__ pos_e, float* __restrict__ H)
{
  int row = blockIdx.x; int t = threadIdx.x;
  float* hr = H + (size_t)row*EMB;
  if (row >= MROWS) { hr[t]=0.f; hr[t+256]=0.f; hr[t+512]=0.f; return; }
  int b = row / SEQ; int pos = row - b*SEQ;
#pragma unroll
  for (int c0=0;c0<3;++c0) {
    int c = t + c0*256;
    float v;
    if (pos==0) v = cls[c];
    else {
      size_t idx = ((size_t)(b*2048 + pos-1))*EMB + c;
      v = P[idx] + P[pstride+idx] + P[2*pstride+idx] + P[3*pstride+idx];
    }
    hr[c] = v + pos_e[(size_t)pos*EMB + c];
  }
}

// ---------------- layernorm row -> bf16
__global__ __launch_bounds__(256) void ln_k(const float* __restrict__ H,
    const float* __restrict__ gam, const float* __restrict__ bet,
    unsigned short* __restrict__ Y)
{
  int row = blockIdx.x, t = threadIdx.x;
  const float* hr = H + (size_t)row*EMB;
  float v0 = hr[t], v1 = hr[t+256], v2 = hr[t+512];
  float s = v0+v1+v2;
#pragma unroll
  for (int off=32; off>=1; off>>=1) s += __shfl_down(s, off);
  __shared__ float r1[4], r2[4];
  if ((t&63)==0) r1[t>>6] = s;
  __syncthreads();
  float mean = (r1[0]+r1[1]+r1[2]+r1[3]) * (1.f/768.f);
  float d0=v0-mean, d1=v1-mean, d2=v2-mean;
  float q = d0*d0+d1*d1+d2*d2;
#pragma unroll
  for (int off=32; off>=1; off>>=1) q += __shfl_down(q, off);
  if ((t&63)==0) r2[t>>6] = q;
  __syncthreads();
  float rstd = rsqrtf((r2[0]+r2[1]+r2[2]+r2[3])*(1.f/768.f) + 1e-5f);
  unsigned short* yr = Y + (size_t)row*EMB;
  yr[t]     = f2bf(d0*rstd*gam[t]     + bet[t]);
  yr[t+256] = f2bf(d1*rstd*gam[t+256] + bet[t+256]);
  yr[t+512] = f2bf(d2*rstd*gam[t+512] + bet[t+512]);
}

// ---------------- fused: H += sum_{s<S} P[s]; Y = LN(H)
template<int S>
__global__ __launch_bounds__(256) void ln_red_k(float* __restrict__ H,
    const float* __restrict__ P, size_t pstride,
    const float* __restrict__ gam, const float* __restrict__ bet,
    unsigned short* __restrict__ Y)
{
  int row = blockIdx.x, t = threadIdx.x;
  size_t base = (size_t)row*EMB;
  float v[3];
#pragma unroll
  for (int c0=0;c0<3;++c0) {
    size_t idx = base + t + c0*256;
    float h = H[idx];
#pragma unroll
    for (int s=0;s<S;++s) h += P[(size_t)s*pstride + idx];
    H[idx] = h; v[c0] = h;
  }
  float s = v[0]+v[1]+v[2];
#pragma unroll
  for (int off=32; off>=1; off>>=1) s += __shfl_down(s, off);
  __shared__ float r1[4], r2[4];
  if ((t&63)==0) r1[t>>6] = s;
  __syncthreads();
  float mean = (r1[0]+r1[1]+r1[2]+r1[3]) * (1.f/768.f);
  float d0=v[0]-mean, d1=v[1]-mean, d2=v[2]-mean;
  float q = d0*d0+d1*d1+d2*d2;
#pragma unroll
  for (int off=32; off>=1; off>>=1) q += __shfl_down(q, off);
  if ((t&63)==0) r2[t>>6] = q;
  __syncthreads();
  float rstd = rsqrtf((r2[0]+r2[1]+r2[2]+r2[3])*(1.f/768.f) + 1e-5f);
  unsigned short* yr = Y + base;
  yr[t]     = f2bf(d0*rstd*gam[t]     + bet[t]);
  yr[t+256] = f2bf(d1*rstd*gam[t+256] + bet[t+256]);
  yr[t+512] = f2bf(d2*rstd*gam[t+512] + bet[t+512]);
}

// ---------------- final layernorm on cls rows -> fp32 out
template<int S>
__global__ __launch_bounds__(256) void final_ln_red_k(const float* __restrict__ H,
   const float* __restrict__ P, size_t pstride,
   const float* __restrict__ gam, const float* __restrict__ bet, float* __restrict__ out)
{
  int b = blockIdx.x, t = threadIdx.x;
  size_t base = (size_t)(b*SEQ)*EMB;
  float v[3];
#pragma unroll
  for (int c0=0;c0<3;++c0) {
    size_t idx = base + t + c0*256;
    float h = H[idx];
#pragma unroll
    for (int s=0;s<S;++s) h += P[(size_t)s*pstride + idx];
    v[c0] = h;
  }
  float s = v[0]+v[1]+v[2];
#pragma unroll
  for (int off=32; off>=1; off>>=1) s += __shfl_down(s, off);
  __shared__ float r1[4], r2[4];
  if ((t&63)==0) r1[t>>6] = s;
  __syncthreads();
  float mean = (r1[0]+r1[1]+r1[2]+r1[3]) * (1.f/768.f);
  float d0=v[0]-mean, d1=v[1]-mean, d2=v[2]-mean;
  float q = d0*d0+d1*d1+d2*d2;
#pragma unroll
  for (int off=32; off>=1; off>>=1) q += __shfl_down(q, off);
  if ((t&63)==0) r2[t>>6] = q;
  __syncthreads();
  float rstd = rsqrtf((r2[0]+r2[1]+r2[2]+r2[3])*(1.f/768.f) + 1e-5f);
  out[b*EMB + t]     = d0*rstd*gam[t]     + bet[t];
  out[b*EMB + t+256] = d1*rstd*gam[t+256] + bet[t+256];
  out[b*EMB + t+512] = d2*rstd*gam[t+512] + bet[t+512];
}

// ---------------- GEMM: 128x128 tile, 512 threads / 8 waves (r12 config, passed)
template<int MODE, int NSPLIT>
__global__ __launch_bounds__(512) void gemm_k(
    const unsigned short* __restrict__ A,
    const unsigned short* __restrict__ Bt,
    const float* __restrict__ bias,
    unsigned short* __restrict__ Cb,
    float* __restrict__ Cf,
    int K, int ldc, size_t splitStride)
{
  __shared__ __attribute__((aligned(16))) unsigned short lA[3][128*32];
  __shared__ __attribute__((aligned(16))) unsigned short lB[3][128*32];
  const int tid = threadIdx.x;
  const int w = tid>>6, lane = tid&63, g = lane>>4, l16 = lane&15;
  const int lr = lane>>2;
  const int lcs = (((lane&3) ^ ((lane>>3)&3)))*8;
  const int swz = ((g ^ ((l16>>1)&3)))*8;
  const int nwg = gridDim.x*gridDim.y;
  const int id = blockIdx.y*gridDim.x + blockIdx.x;
  const int q = nwg>>3, r = nwg&7, xc = id&7, si = id>>3;
  const int nid = (xc<r ? xc*(q+1) : r*(q+1)+(xc-r)*q) + si;
  const int tm = nid / gridDim.x;
  const int tn = nid - tm*gridDim.x;
  const int kchunk = K / NSPLIT;
  const int kofs = (NSPLIT>1) ? blockIdx.z * kchunk : 0;
  const unsigned short* Ab = A + (size_t)tm*128*K + kofs;
  const unsigned short* Bb = Bt + (size_t)tn*128*K + kofs;
  const int wm = (w>>2)*64, wn = (w&3)*32;
  f4 acc[4][2] = {};
  const int nkt = kchunk>>5;

  auto STAGE = [&](int buf, int kt){
    const size_t ko = (size_t)(kt*32 + lcs);
    gl_lds16(Ab + (size_t)(w*16 + lr)*K + ko, ((char*)lA[buf]) + w*1024);
    gl_lds16(Bb + (size_t)(w*16 + lr)*K + ko, ((char*)lB[buf]) + w*1024);
  };

  STAGE(0, 0);
  STAGE(1, 1);
  for (int kt=0; kt<nkt; ++kt) {
    const int cur = kt % 3;
    if (kt+2 < nkt) {
      STAGE((kt+2)%3, kt+2);
      asm volatile("s_waitcnt vmcnt(4)" ::: "memory");
    } else if (kt+1 < nkt) {
      asm volatile("s_waitcnt vmcnt(2)" ::: "memory");
    } else {
      asm volatile("s_waitcnt vmcnt(0)" ::: "memory");
    }
    __builtin_amdgcn_sched_barrier(0);
    __builtin_amdgcn_s_barrier();
    bs8 af[4], bf[2];
#pragma unroll
    for (int mi=0;mi<4;++mi) af[mi] = *(const bs8*)(lA[cur] + (wm+mi*16+l16)*32 + swz);
#pragma unroll
    for (int ni=0;ni<2;++ni) bf[ni] = *(const bs8*)(lB[cur] + (wn+ni*16+l16)*32 + swz);
    asm volatile("s_waitcnt lgkmcnt(0)" ::: "memory");
    __builtin_amdgcn_sched_barrier(0);
    __builtin_amdgcn_s_barrier();
#pragma unroll
    for (int mi=0;mi<4;++mi)
#pragma unroll
      for (int ni=0;ni<2;++ni)
        acc[mi][ni] = __builtin_amdgcn_mfma_f32_16x16x32_bf16(af[mi], bf[ni], acc[mi][ni], 0,0,0);
  }
  const float bscale = (NSPLIT==1 || blockIdx.z==0) ? 1.f : 0.f;
#pragma unroll
  for (int mi=0;mi<4;++mi)
#pragma unroll
    for (int ni=0;ni<2;++ni) {
      int col = tn*128 + wn + ni*16 + l16;
      float bv = bias[col]*bscale;
#pragma unroll
      for (int r0=0;r0<4;++r0) {
        int row = tm*128 + wm + mi*16 + g*4 + r0;
        float val = acc[mi][ni][r0] + bv;
        if (MODE==1) val = gelu_f(val);
        if (MODE<=1) Cb[(size_t)row*ldc + col] = f2bf(val);
        else Cf[(size_t)blockIdx.z*splitStride + (size_t)row*ldc + col] = val;
      }
    }
}

// ---------------- dilated attention, key-split: one block = 64 q-rows x ONE
// 128-key chunk. No chunk loop, single-pass softmax, partial O/LSE per chunk.
// Partial layout: O[b][seg][hd][ck][512][64] bf16, L[...][ck][512] f32.
__global__ __launch_bounds__(256) void attn_all_k(
    const unsigned short* __restrict__ qkv,
    unsigned short* __restrict__ O1, float* __restrict__ L1,
    unsigned short* __restrict__ O2, float* __restrict__ L2,
    unsigned short* __restrict__ O3, float* __restrict__ L3)
{
  __shared__ __attribute__((aligned(16))) unsigned short lsm[128*72 + 64*136];
  unsigned short* lK  = lsm;
  unsigned short* lVt = lsm + 128*72;
  const int tid = threadIdx.x;
  const int w = tid>>6, lane = tid&63, g = lane>>4, l16 = lane&15;

  int id2 = (blockIdx.x & 7)*960 + (blockIdx.x >> 3);   // 7680 = 8*960 bijective
  const int ck = id2 & 3; int id = id2 >> 2;
  int R, WSZ, NSEG; unsigned short* OB; float* LB;
  if (id < 960)       { R=1; WSZ=512;  NSEG=5; OB=O1; LB=L1; }
  else if (id < 1536) { id -= 960;  R=2; WSZ=1024; NSEG=3; OB=O2; LB=L2; }
  else                { id -= 1536; R=4; WSZ=2048; NSEG=2; OB=O3; LB=L3; }
  const int qt = id & 7; int rest = id >> 3;
  const int seg = rest % NSEG; const int bh = rest / NSEG;
  const int b = bh / NHEADS, hd = bh % NHEADS;
  const int hr = hd % R;
  const int kbase = seg*WSZ + hr;
  const int cofs = ck*128;
  bs8 z = {0,0,0,0,0,0,0,0};
  size_t obase = (((size_t)(b*NSEG + seg)*NHEADS + hd)*4 + ck)*512;

  // no valid q-row, or no valid key in this chunk -> deterministic defaults
  if (kbase + qt*64*R >= SEQ || kbase + cofs*R >= SEQ) {
    size_t ob2 = obase + qt*64;
    int row = tid>>2, cb = (tid&3)*16;
    *(bs8*)(&OB[(ob2 + row)*64 + cb])     = z;
    *(bs8*)(&OB[(ob2 + row)*64 + cb + 8]) = z;
    if (tid < 64) LB[ob2 + tid] = NEGV;
    return;
  }

  const int j0 = qt*64 + w*16;
  const unsigned short* qkvb = qkv + (size_t)b*SEQ*QKVW;

  bs8 qf0 = z, qf1 = z;
  {
    int qpos = kbase + (j0 + l16)*R;
    if (qpos < SEQ) {
      const unsigned short* qrow = qkvb + (size_t)qpos*QKVW + hd*64 + g*8;
      qf0 = *(const bs8*)(qrow);
      qf1 = *(const bs8*)(qrow + 32);
    }
  }

  // stage K/V for this chunk
  const int dbK = tid&7, kkKb = tid>>3;
  const int kkV = tid&127, dbV0 = tid>>7;
  const unsigned short* pK = qkvb + (size_t)(kbase + (cofs + kkKb)*R)*QKVW + EMB + hd*64 + dbK*8;
  const unsigned short* pV = qkvb + (size_t)(kbase + (cofs + kkV)*R)*QKVW + 1536 + hd*64 + dbV0*8;
  const size_t stepIt = (size_t)32*R*QKVW;
  const bool fullc = (kbase + (cofs + 127)*R) < SEQ;
  bs8 kreg[4], vreg[4];
  if (fullc) {
#pragma unroll
    for (int it=0; it<4; ++it) kreg[it] = *(const bs8*)(pK + (size_t)it*stepIt);
#pragma unroll
    for (int it=0; it<4; ++it) vreg[it] = *(const bs8*)(pV + it*16);
  } else {
#pragma unroll
    for (int it=0; it<4; ++it)
      kreg[it] = (kbase + (cofs + kkKb + it*32)*R < SEQ)
                 ? *(const bs8*)(pK + (size_t)it*stepIt) : z;
    const bool vv = (kbase + (cofs + kkV)*R) < SEQ;
#pragma unroll
    for (int it=0; it<4; ++it) vreg[it] = vv ? *(const bs8*)(pV + it*16) : z;
  }
#pragma unroll
  for (int it=0; it<4; ++it) {
    *(bs8*)(lK + (kkKb + it*32)*72 + dbK*8) = kreg[it];
#pragma unroll
    for (int ii=0; ii<8; ++ii) lVt[((dbV0+it*2)*8+ii)*136 + kkV] = (unsigned short)vreg[it][ii];
  }
  __syncthreads();

  // QK^T (raw scores)
  f4 sc[8];
  __builtin_amdgcn_s_setprio(1);
#pragma unroll
  for (int kt=0; kt<8; ++kt) {
    int key = kt*16 + l16;
    bs8 kf0 = *(const bs8*)(lK + key*72 + g*8);
    bs8 kf1 = *(const bs8*)(lK + key*72 + 32 + g*8);
    f4 acc = {0.f,0.f,0.f,0.f};
    acc = __builtin_amdgcn_mfma_f32_16x16x32_bf16(qf0, kf0, acc, 0,0,0);
    acc = __builtin_amdgcn_mfma_f32_16x16x32_bf16(qf1, kf1, acc, 0,0,0);
    sc[kt] = acc;
  }
  __builtin_amdgcn_s_setprio(0);
  __syncthreads();                 // all waves done reading lK -> Pl may overwrite it

  if (!fullc) {
#pragma unroll
    for (int kt=0; kt<8; ++kt) {
      bool kvld = (kbase + (cofs + kt*16 + l16)*R) < SEQ;
#pragma unroll
      for (int r=0;r<4;++r) sc[kt][r] = kvld ? sc[kt][r] : NEGV;
    }
  }
  // single-pass softmax (scaled max), per 16-lane row group
  float rm[4], rs[4];
#pragma unroll
  for (int r=0;r<4;++r) {
    float mx = sc[0][r];
#pragma unroll
    for (int kt=1;kt<8;++kt) mx = fmaxf(mx, sc[kt][r]);
    mx = fmaxf(mx, __shfl_xor(mx, 1));
    mx = fmaxf(mx, __shfl_xor(mx, 2));
    mx = fmaxf(mx, __shfl_xor(mx, 4));
    mx = fmaxf(mx, __shfl_xor(mx, 8));
    rm[r] = mx*0.125f;
  }
#pragma unroll
  for (int r=0;r<4;++r) {
    float sm = 0.f;
    float nrm = -rm[r];
#pragma unroll
    for (int kt=0;kt<8;++kt) {
      float p = __expf(__builtin_fmaf(sc[kt][r], 0.125f, nrm));
      sc[kt][r] = p; sm += p;
    }
    rs[r] = sm;
  }
  // P -> LDS (Pl aliases lK, per-wave region, granule-swizzled)
  unsigned short* Plw = lK + w*16*136;
#pragma unroll
  for (int kt=0;kt<8;++kt)
#pragma unroll
    for (int r=0;r<4;++r) {
      int row = g*4+r;
      int gr = (kt*2 + (l16>>3)) ^ ((row>>3)&1);
      Plw[row*136 + gr*8 + (l16&7)] = f2bf_fast(sc[kt][r]);
    }
  f4 oacc[4] = {};
  __builtin_amdgcn_s_setprio(1);
#pragma unroll
  for (int ks=0; ks<4; ++ks) {
    int grp = ((ks*4+g) ^ ((l16>>3)&1))*8;
    bs8 pa = *(const bs8*)(Plw + l16*136 + grp);
#pragma unroll
    for (int dt=0; dt<4; ++dt) {
      bs8 vb = *(const bs8*)(lVt + (dt*16+l16)*136 + ks*32 + g*8);
      oacc[dt] = __builtin_amdgcn_mfma_f32_16x16x32_bf16(pa, vb, oacc[dt], 0,0,0);
    }
  }
  __builtin_amdgcn_s_setprio(0);

#pragma unroll
  for (int r=0;r<4;++r) {
    float s = rs[r];
    s += __shfl_xor(s, 1); s += __shfl_xor(s, 2);
    s += __shfl_xor(s, 4); s += __shfl_xor(s, 8);
    rs[r] = s;
  }

#pragma unroll
  for (int dt=0; dt<4; ++dt)
#pragma unroll
    for (int r=0;r<4;++r) {
      int j = j0 + g*4 + r;
      OB[(obase + j)*64 + dt*16 + l16] = f2bf(oacc[dt][r] / rs[r]);
    }
  if (l16 == 0) {
#pragma unroll
    for (int r=0;r<4;++r) LB[obase + j0 + g*4 + r] = rm[r] + __logf(rs[r]);
  }
}

// ---------------- combine 12 partials (4 chunks x 3 branches) via lse softmax
__global__ __launch_bounds__(256) void attn_combine_k(
   const unsigned short* __restrict__ o1, const float* __restrict__ l1,
   const unsigned short* __restrict__ o2, const float* __restrict__ l2,
   const unsigned short* __restrict__ o3, const float* __restrict__ l3,
   unsigned short* __restrict__ attn)
{
  int row = blockIdx.x; int t = threadIdx.x;
  unsigned short* arow = attn + (size_t)row*EMB;
  if (row >= MROWS) { arow[t]=0; arow[t+256]=0; arow[t+512]=0; return; }
  int b = row / SEQ, pos = row - (row/SEQ)*SEQ;
#pragma unroll
  for (int c0=0; c0<3; ++c0) {
    int cc = t + c0*256;
    int hd = cc >> 6, d = cc & 63;
    float La[12], Oa[12];
    {
      int seg = pos >> 9; int j = pos & 511;
      size_t base0 = (((size_t)(b*5 + seg)*NHEADS + hd)*4)*512 + j;
#pragma unroll
      for (int ck=0;ck<4;++ck) {
        La[ck] = l1[base0 + ck*512];
        Oa[ck] = bf2f(o1[(base0 + ck*512)*64 + d]);
      }
    }
    if ((pos & 1) == (hd & 1)) {
      int seg = pos >> 10; int j = ((pos & 1023) - (hd&1)) >> 1;
      size_t base0 = (((size_t)(b*3 + seg)*NHEADS + hd)*4)*512 + j;
#pragma unroll
      for (int ck=0;ck<4;++ck) {
        La[4+ck] = l2[base0 + ck*512];
        Oa[4+ck] = bf2f(o2[(base0 + ck*512)*64 + d]);
      }
    } else {
#pragma unroll
      for (int ck=0;ck<4;++ck) { La[4+ck] = NEGV; Oa[4+ck] = 0.f; }
    }
    if ((pos & 3) == (hd & 3)) {
      int seg = pos >> 11; int j = ((pos & 2047) - (hd&3)) >> 2;
      size_t base0 = (((size_t)(b*2 + seg)*NHEADS + hd)*4)*512 + j;
#pragma unroll
      for (int ck=0;ck<4;++ck) {
        La[8+ck] = l3[base0 + ck*512];
        Oa[8+ck] = bf2f(o3[(base0 + ck*512)*64 + d]);
      }
    } else {
#pragma unroll
      for (int ck=0;ck<4;++ck) { La[8+ck] = NEGV; Oa[8+ck] = 0.f; }
    }
    float M = La[0];
#pragma unroll
    for (int i=1;i<12;++i) M = fmaxf(M, La[i]);
    float acc = 0.f, wsum = 0.f;
#pragma unroll
    for (int i=0;i<12;++i) {
      float e = __expf(La[i] - M);
      acc += e * Oa[i]; wsum += e;
    }
    arow[cc] = f2bf(acc / wsum);
  }
}

extern "C" void kernel_launch(void* const* d_in, const int* in_sizes, int n_in,
                              void* d_out, int out_size, void* d_ws, size_t ws_size,
                              hipStream_t stream) {
  const float* x       = (const float*)d_in[0];
  const float* conv_w  = (const float*)d_in[1];
  const float* conv_b  = (const float*)d_in[2];
  const float* cls     = (const float*)d_in[3];
  const float* pos_e   = (const float*)d_in[4];
  const float* ln1_g   = (const float*)d_in[5];
  const float* ln1_b   = (const float*)d_in[6];
  const float* wq      = (const float*)d_in[7];
  const float* bq      = (const float*)d_in[8];
  const float* wk      = (const float*)d_in[9];
  const float* bk      = (const float*)d_in[10];
  const float* wv      = (const float*)d_in[11];
  const float* bv      = (const float*)d_in[12];
  const float* wo      = (const float*)d_in[13];
  const float* bo      = (const float*)d_in[14];
  const float* ln2_g   = (const float*)d_in[15];
  const float* ln2_b   = (const float*)d_in[16];
  const float* w1      = (const float*)d_in[17];
  const float* b1      = (const float*)d_in[18];
  const float* w2      = (const float*)d_in[19];
  const float* b2      = (const float*)d_in[20];
  const float* nf_g    = (const float*)d_in[21];
  const float* nf_b    = (const float*)d_in[22];

  char* ws = (char*)d_ws;
  size_t off = 0;
  auto alloc = [&](size_t bytes)->char* {
    char* p = ws + off; off += (bytes + 255) & ~(size_t)255; return p;
  };
  unsigned short* wqkv_t = (unsigned short*)alloc((size_t)12*2304*768*2);
  unsigned short* wo_t   = (unsigned short*)alloc((size_t)12*768*768*2);
  unsigned short* w1_t   = (unsigned short*)alloc((size_t)12*3072*768*2);
  unsigned short* w2_t   = (unsigned short*)alloc((size_t)12*768*3072*2);
  unsigned short* cw_b   = (unsigned short*)alloc((size_t)768*4096*2);
  float* bqkv            = (float*)alloc((size_t)12*2304*4);
  unsigned short* Xp     = (unsigned short*)alloc((size_t)4096*4096*2);
  float* H               = (float*)alloc((size_t)MPAD*768*4);
  float* P               = (float*)alloc((size_t)4*MPAD*768*4);
  unsigned short* Y      = (unsigned short*)alloc((size_t)MPAD*768*2);
  unsigned short* QKV    = (unsigned short*)alloc((size_t)MPAD*2304*2);
  unsigned short* ATT    = (unsigned short*)alloc((size_t)MPAD*768*2);
  unsigned short* Y2     = (unsigned short*)alloc((size_t)MPAD*3072*2);
  unsigned short* O1 = (unsigned short*)alloc((size_t)2*5*12*4*512*64*2);
  unsigned short* O2 = (unsigned short*)alloc((size_t)2*3*12*4*512*64*2);
  unsigned short* O3 = (unsigned short*)alloc((size_t)2*2*12*4*512*64*2);
  float* L1 = (float*)alloc((size_t)2*5*12*4*512*4);
  float* L2 = (float*)alloc((size_t)2*3*12*4*512*4);
  float* L3 = (float*)alloc((size_t)2*2*12*4*512*4);
  const size_t PSTR = (size_t)MPAD*768;

  dim3 tb(32,8);
  wtr_k<<<dim3(24,24,12), tb, 0, stream>>>(wq, wqkv_t, 768, 768, 2304, 0);
  wtr_k<<<dim3(24,24,12), tb, 0, stream>>>(wk, wqkv_t, 768, 768, 2304, 768);
  wtr_k<<<dim3(24,24,12), tb, 0, stream>>>(wv, wqkv_t, 768, 768, 2304, 1536);
  wtr_k<<<dim3(24,24,12), tb, 0, stream>>>(wo, wo_t, 768, 768, 768, 0);
  wtr_k<<<dim3(24,96,12), tb, 0, stream>>>(w1, w1_t, 768, 3072, 3072, 0);
  wtr_k<<<dim3(96,24,12), tb, 0, stream>>>(w2, w2_t, 3072, 768, 768, 0);
  castconv_k<<<3072,256,0,stream>>>(conv_w, cw_b);
  biascat_k<<<108,256,0,stream>>>(bq,bk,bv,bqkv);
  patchify_k<<<16384,256,0,stream>>>(x, Xp);
  gemm_k<3,4><<<dim3(6,32,4),512,0,stream>>>(Xp, cw_b, conv_b, nullptr, P, 4096, 768, PSTR);
  assemble_k<<<MPAD,256,0,stream>>>(P, PSTR, cls, pos_e, H);

  for (int l=0;l<12;++l) {
    if (l==0) ln_k<<<MPAD,256,0,stream>>>(H, ln1_g, ln1_b, Y);
    else ln_red_k<2><<<MPAD,256,0,stream>>>(H, P, PSTR, ln1_g + l*768, ln1_b + l*768, Y);
    gemm_k<0,1><<<dim3(18,33),512,0,stream>>>(Y, wqkv_t + (size_t)l*2304*768, bqkv + l*2304, QKV, nullptr, 768, 2304, 0);
    attn_all_k<<<7680,256,0,stream>>>(QKV, O1,L1,O2,L2,O3,L3);
    attn_combine_k<<<MPAD,256,0,stream>>>(O1,L1,O2,L2,O3,L3, ATT);
    gemm_k<3,2><<<dim3(6,33,2),512,0,stream>>>(ATT, wo_t + (size_t)l*768*768, bo + l*768, nullptr, P, 768, 768, PSTR);
    ln_red_k<2><<<MPAD,256,0,stream>>>(H, P, PSTR, ln2_g + l*768, ln2_b + l*768, Y);
    gemm_k<1,1><<<dim3(24,33),512,0,stream>>>(Y, w1_t + (size_t)l*3072*768, b1 + l*3072, Y2, nullptr, 768, 3072, 0);
    gemm_k<3,2><<<dim3(6,33,2),512,0,stream>>>(Y2, w2_t + (size_t)l*768*3072, b2 + l*768, nullptr, P, 3072, 768, PSTR);
  }
  final_ln_red_k<2><<<2,256,0,stream>>>(H, P, PSTR, nf_g, nf_b, (float*)d_out);
}

// Round 15
// 2602.309 us; speedup vs baseline: 1.1517x; 1.0198x over previous
//
#include <hip/hip_runtime.h>
#include <math.h>

#define SEQ 2049
#define EMB 768
#define NHEADS 12
#define QKVW 2304
#define MROWS 4098
#define MPAD 4224
#define NEGV -1000000000.0f

typedef short bs8 __attribute__((ext_vector_type(8)));
typedef float f4 __attribute__((ext_vector_type(4)));

__device__ __forceinline__ unsigned short f2bf(float f){
  union { float f; unsigned u; } x; x.f = f;
  unsigned r = x.u + 0x7fffu + ((x.u >> 16) & 1u);
  return (unsigned short)(r >> 16);
}
__device__ __forceinline__ unsigned short f2bf_fast(float f){
  union { float f; unsigned u; } x; x.f = f;
  return (unsigned short)((x.u + 0x8000u) >> 16);
}
__device__ __forceinline__ float bf2f(unsigned short u){
  union { unsigned u; float f; } x; x.u = ((unsigned)u) << 16; return x.f;
}

__device__ __forceinline__ float gelu_f(float x){
  float ax = fabsf(x)*0.70710678f;
  float t = 1.f/(1.f + 0.3275911f*ax);
  float p = t*(0.254829592f + t*(-0.284496736f + t*(1.421413741f
            + t*(-1.453152027f + t*1.061405429f))));
  float erfv = 1.f - p*__expf(-ax*ax);
  float s = (x >= 0.f) ? erfv : -erfv;
  return 0.5f*x*(1.f + s);
}

__device__ __forceinline__ void gl_lds16(const void* g, void* l){
  __builtin_amdgcn_global_load_lds((const __attribute__((address_space(1))) void*)g,
                                   (__attribute__((address_space(3))) void*)l, 16, 0, 0);
}

// ---------------- weight transpose fp32 (L,K,N) -> bf16 dst[(l*LD+NOFF+n)*K+k]
__global__ void wtr_k(const float* __restrict__ src, unsigned short* __restrict__ dst,
                      int K, int N, int LD, int NOFF)
{
  __shared__ float tile[32][33];
  int k0 = blockIdx.x*32, n0 = blockIdx.y*32, z = blockIdx.z;
  int tx = threadIdx.x, ty = threadIdx.y;
  const float* s = src + (size_t)z*K*N;
#pragma unroll
  for (int i=0;i<4;++i)
    tile[ty*4+i][tx] = s[(size_t)(k0+ty*4+i)*N + n0+tx];
  __syncthreads();
  unsigned short* dz = dst + ((size_t)z*LD + NOFF)*K;
#pragma unroll
  for (int i=0;i<4;++i)
    dz[(size_t)(n0+ty*4+i)*K + k0+tx] = f2bf(tile[tx][ty*4+i]);
}

__global__ void castconv_k(const float* __restrict__ src, unsigned short* __restrict__ dst){
  size_t i = ((size_t)blockIdx.x*256 + threadIdx.x)*4;
  float4 f = *(const float4*)(src+i);
  dst[i+0]=f2bf(f.x); dst[i+1]=f2bf(f.y); dst[i+2]=f2bf(f.z); dst[i+3]=f2bf(f.w);
}

__global__ void biascat_k(const float* __restrict__ bq, const float* __restrict__ bk,
                          const float* __restrict__ bv, float* __restrict__ dst){
  int i = blockIdx.x*256+threadIdx.x;
  int l = i/QKVW, c = i%QKVW;
  float v = (c<768) ? bq[l*768+c] : (c<1536 ? bk[l*768+c-768] : bv[l*768+c-1536]);
  dst[i] = v;
}

// ---------------- patch extraction
__global__ void patchify_k(const float* __restrict__ x, unsigned short* __restrict__ Xp)
{
  size_t gid = (size_t)blockIdx.x*256 + threadIdx.x;
  size_t oi = gid*4;
  int row = (int)(oi >> 12);
  int c = (int)(oi & 4095);
  int b = row >> 11; int p = row & 2047;
  int pd = p >> 8, ph = (p>>4)&15, pw = p&15;
  int pz = c >> 8, py = (c>>4)&15, px = c&15;
  size_t src = (((size_t)(b*128 + pd*16+pz)*256) + (size_t)(ph*16+py))*256 + (size_t)(pw*16+px);
  float4 f = *(const float4*)(x+src);
  Xp[oi+0]=f2bf(f.x); Xp[oi+1]=f2bf(f.y); Xp[oi+2]=f2bf(f.z); Xp[oi+3]=f2bf(f.w);
}

// ---------------- assemble h = [cls; sum4(P)] + pos, zero pads
__global__ void assemble_k(const float* __restrict__ P, size_t pstride,
                           const float* __restrict__ cls,
                           const float* __restrict__ pos_e, float* __restrict__ H)
{
  int row = blockIdx.x; int t = threadIdx.x;
  float* hr = H + (size_t)row*EMB;
  if (row >= MROWS) { hr[t]=0.f; hr[t+256]=0.f; hr[t+512]=0.f; return; }
  int b = row / SEQ; int pos = row - b*SEQ;
#pragma unroll
  for (int c0=0;c0<3;++c0) {
    int c = t + c0*256;
    float v;
    if (pos==0) v = cls[c];
    else {
      size_t idx = ((size_t)(b*2048 + pos-1))*EMB + c;
      v = P[idx] + P[pstride+idx] + P[2*pstride+idx] + P[3*pstride+idx];
    }
    hr[c] = v + pos_e[(size_t)pos*EMB + c];
  }
}

// ---------------- layernorm row -> bf16
__global__ __launch_bounds__(256) void ln_k(const float* __restrict__ H,
    const float* __restrict__ gam, const float* __restrict__ bet,
    unsigned short* __restrict__ Y)
{
  int row = blockIdx.x, t = threadIdx.x;
  const float* hr = H + (size_t)row*EMB;
  float v0 = hr[t], v1 = hr[t+256], v2 = hr[t+512];
  float s = v0+v1+v2;
#pragma unroll
  for (int off=32; off>=1; off>>=1) s += __shfl_down(s, off);
  __shared__ float r1[4], r2[4];
  if ((t&63)==0) r1[t>>6] = s;
  __syncthreads();
  float mean = (r1[0]+r1[1]+r1[2]+r1[3]) * (1.f/768.f);
  float d0=v0-mean, d1=v1-mean, d2=v2-mean;
  float q = d0*d0+d1*d1+d2*d2;
#pragma unroll
  for (int off=32; off>=1; off>>=1) q += __shfl_down(q, off);
  if ((t&63)==0) r2[t>>6] = q;
  __syncthreads();
  float rstd = rsqrtf((r2[0]+r2[1]+r2[2]+r2[3])*(1.f/768.f) + 1e-5f);
  unsigned short* yr = Y + (size_t)row*EMB;
  yr[t]     = f2bf(d0*rstd*gam[t]     + bet[t]);
  yr[t+256] = f2bf(d1*rstd*gam[t+256] + bet[t+256]);
  yr[t+512] = f2bf(d2*rstd*gam[t+512] + bet[t+512]);
}

// ---------------- fused: H += sum_{s<S} P[s]; Y = LN(H)
template<int S>
__global__ __launch_bounds__(256) void ln_red_k(float* __restrict__ H,
    const float* __restrict__ P, size_t pstride,
    const float* __restrict__ gam, const float* __restrict__ bet,
    unsigned short* __restrict__ Y)
{
  int row = blockIdx.x, t = threadIdx.x;
  size_t base = (size_t)row*EMB;
  float v[3];
#pragma unroll
  for (int c0=0;c0<3;++c0) {
    size_t idx = base + t + c0*256;
    float h = H[idx];
#pragma unroll
    for (int s=0;s<S;++s) h += P[(size_t)s*pstride + idx];
    H[idx] = h; v[c0] = h;
  }
  float s = v[0]+v[1]+v[2];
#pragma unroll
  for (int off=32; off>=1; off>>=1) s += __shfl_down(s, off);
  __shared__ float r1[4], r2[4];
  if ((t&63)==0) r1[t>>6] = s;
  __syncthreads();
  float mean = (r1[0]+r1[1]+r1[2]+r1[3]) * (1.f/768.f);
  float d0=v[0]-mean, d1=v[1]-mean, d2=v[2]-mean;
  float q = d0*d0+d1*d1+d2*d2;
#pragma unroll
  for (int off=32; off>=1; off>>=1) q += __shfl_down(q, off);
  if ((t&63)==0) r2[t>>6] = q;
  __syncthreads();
  float rstd = rsqrtf((r2[0]+r2[1]+r2[2]+r2[3])*(1.f/768.f) + 1e-5f);
  unsigned short* yr = Y + base;
  yr[t]     = f2bf(d0*rstd*gam[t]     + bet[t]);
  yr[t+256] = f2bf(d1*rstd*gam[t+256] + bet[t+256]);
  yr[t+512] = f2bf(d2*rstd*gam[t+512] + bet[t+512]);
}

// ---------------- final layernorm on cls rows -> fp32 out
template<int S>
__global__ __launch_bounds__(256) void final_ln_red_k(const float* __restrict__ H,
   const float* __restrict__ P, size_t pstride,
   const float* __restrict__ gam, const float* __restrict__ bet, float* __restrict__ out)
{
  int b = blockIdx.x, t = threadIdx.x;
  size_t base = (size_t)(b*SEQ)*EMB;
  float v[3];
#pragma unroll
  for (int c0=0;c0<3;++c0) {
    size_t idx = base + t + c0*256;
    float h = H[idx];
#pragma unroll
    for (int s=0;s<S;++s) h += P[(size_t)s*pstride + idx];
    v[c0] = h;
  }
  float s = v[0]+v[1]+v[2];
#pragma unroll
  for (int off=32; off>=1; off>>=1) s += __shfl_down(s, off);
  __shared__ float r1[4], r2[4];
  if ((t&63)==0) r1[t>>6] = s;
  __syncthreads();
  float mean = (r1[0]+r1[1]+r1[2]+r1[3]) * (1.f/768.f);
  float d0=v[0]-mean, d1=v[1]-mean, d2=v[2]-mean;
  float q = d0*d0+d1*d1+d2*d2;
#pragma unroll
  for (int off=32; off>=1; off>>=1) q += __shfl_down(q, off);
  if ((t&63)==0) r2[t>>6] = q;
  __syncthreads();
  float rstd = rsqrtf((r2[0]+r2[1]+r2[2]+r2[3])*(1.f/768.f) + 1e-5f);
  out[b*EMB + t]     = d0*rstd*gam[t]     + bet[t];
  out[b*EMB + t+256] = d1*rstd*gam[t+256] + bet[t+256];
  out[b*EMB + t+512] = d2*rstd*gam[t+512] + bet[t+512];
}

// ---------------- GEMM: 128x128 tile, 512 thr / 8 waves, BK=64 steps
// (two verified 32-K subtiles per step), 2 LDS buffers, vmcnt(4) steady state.
// MODE 0: bf16 out +bias; 1: bf16 out +bias+gelu; 3: f32 split-partial write
template<int MODE, int NSPLIT>
__global__ __launch_bounds__(512) void gemm_k(
    const unsigned short* __restrict__ A,
    const unsigned short* __restrict__ Bt,
    const float* __restrict__ bias,
    unsigned short* __restrict__ Cb,
    float* __restrict__ Cf,
    int K, int ldc, size_t splitStride)
{
  __shared__ __attribute__((aligned(16))) unsigned short lA[2][2][128*32];
  __shared__ __attribute__((aligned(16))) unsigned short lB[2][2][128*32];
  const int tid = threadIdx.x;
  const int w = tid>>6, lane = tid&63, g = lane>>4, l16 = lane&15;
  const int lr = lane>>2;
  const int lcs = (((lane&3) ^ ((lane>>3)&3)))*8;   // pre-swizzled source col-group
  const int swz = ((g ^ ((l16>>1)&3)))*8;           // matching read offset
  const int nwg = gridDim.x*gridDim.y;
  const int id = blockIdx.y*gridDim.x + blockIdx.x;
  const int q = nwg>>3, r = nwg&7, xc = id&7, si = id>>3;
  const int nid = (xc<r ? xc*(q+1) : r*(q+1)+(xc-r)*q) + si;
  const int tm = nid / gridDim.x;
  const int tn = nid - tm*gridDim.x;
  const int kchunk = K / NSPLIT;
  const int kofs = (NSPLIT>1) ? blockIdx.z * kchunk : 0;
  const unsigned short* Ab = A + (size_t)tm*128*K + kofs;
  const unsigned short* Bb = Bt + (size_t)tn*128*K + kofs;
  const int wm = (w>>2)*64, wn = (w&3)*32;          // 2x4 wave grid, 64x32 per wave
  f4 acc[4][2] = {};
  const int nkt = kchunk>>6;                        // BK=64 steps

  auto STAGE = [&](int buf, int kt){
    const size_t ko = (size_t)(kt*64 + lcs);
    gl_lds16(Ab + (size_t)(w*16 + lr)*K + ko,      ((char*)&lA[buf][0][0]) + w*1024);
    gl_lds16(Ab + (size_t)(w*16 + lr)*K + ko + 32, ((char*)&lA[buf][1][0]) + w*1024);
    gl_lds16(Bb + (size_t)(w*16 + lr)*K + ko,      ((char*)&lB[buf][0][0]) + w*1024);
    gl_lds16(Bb + (size_t)(w*16 + lr)*K + ko + 32, ((char*)&lB[buf][1][0]) + w*1024);
  };

  STAGE(0, 0);
  for (int kt=0; kt<nkt; ++kt) {
    const int cur = kt & 1;
    if (kt+1 < nkt) {
      STAGE(cur^1, kt+1);
      asm volatile("s_waitcnt vmcnt(4)" ::: "memory");   // kt's 4 loads done
    } else {
      asm volatile("s_waitcnt vmcnt(0)" ::: "memory");
    }
    __builtin_amdgcn_sched_barrier(0);
    __builtin_amdgcn_s_barrier();          // buf[cur] ready for all waves
    bs8 af[2][4], bf[2][2];
#pragma unroll
    for (int s=0;s<2;++s) {
#pragma unroll
      for (int mi=0;mi<4;++mi) af[s][mi] = *(const bs8*)(&lA[cur][s][0] + (wm+mi*16+l16)*32 + swz);
#pragma unroll
      for (int ni=0;ni<2;++ni) bf[s][ni] = *(const bs8*)(&lB[cur][s][0] + (wn+ni*16+l16)*32 + swz);
    }
    asm volatile("s_waitcnt lgkmcnt(0)" ::: "memory");
    __builtin_amdgcn_sched_barrier(0);
    __builtin_amdgcn_s_barrier();          // all reads of buf[cur] done -> reusable
#pragma unroll
    for (int s=0;s<2;++s)
#pragma unroll
      for (int mi=0;mi<4;++mi)
#pragma unroll
        for (int ni=0;ni<2;++ni)
          acc[mi][ni] = __builtin_amdgcn_mfma_f32_16x16x32_bf16(af[s][mi], bf[s][ni], acc[mi][ni], 0,0,0);
  }
  const float bscale = (NSPLIT==1 || blockIdx.z==0) ? 1.f : 0.f;
#pragma unroll
  for (int mi=0;mi<4;++mi)
#pragma unroll
    for (int ni=0;ni<2;++ni) {
      int col = tn*128 + wn + ni*16 + l16;
      float bv = bias[col]*bscale;
#pragma unroll
      for (int r0=0;r0<4;++r0) {
        int row = tm*128 + wm + mi*16 + g*4 + r0;
        float val = acc[mi][ni][r0] + bv;
        if (MODE==1) val = gelu_f(val);
        if (MODE<=1) Cb[(size_t)row*ldc + col] = f2bf(val);
        else Cf[(size_t)blockIdx.z*splitStride + (size_t)row*ldc + col] = val;
      }
    }
}

// ---------------- dilated attention, key-split (r14 config, passed)
__global__ __launch_bounds__(256) void attn_all_k(
    const unsigned short* __restrict__ qkv,
    unsigned short* __restrict__ O1, float* __restrict__ L1,
    unsigned short* __restrict__ O2, float* __restrict__ L2,
    unsigned short* __restrict__ O3, float* __restrict__ L3)
{
  __shared__ __attribute__((aligned(16))) unsigned short lsm[128*72 + 64*136];
  unsigned short* lK  = lsm;
  unsigned short* lVt = lsm + 128*72;
  const int tid = threadIdx.x;
  const int w = tid>>6, lane = tid&63, g = lane>>4, l16 = lane&15;

  int id2 = (blockIdx.x & 7)*960 + (blockIdx.x >> 3);   // 7680 = 8*960 bijective
  const int ck = id2 & 3; int id = id2 >> 2;
  int R, WSZ, NSEG; unsigned short* OB; float* LB;
  if (id < 960)       { R=1; WSZ=512;  NSEG=5; OB=O1; LB=L1; }
  else if (id < 1536) { id -= 960;  R=2; WSZ=1024; NSEG=3; OB=O2; LB=L2; }
  else                { id -= 1536; R=4; WSZ=2048; NSEG=2; OB=O3; LB=L3; }
  const int qt = id & 7; int rest = id >> 3;
  const int seg = rest % NSEG; const int bh = rest / NSEG;
  const int b = bh / NHEADS, hd = bh % NHEADS;
  const int hr = hd % R;
  const int kbase = seg*WSZ + hr;
  const int cofs = ck*128;
  bs8 z = {0,0,0,0,0,0,0,0};
  size_t obase = (((size_t)(b*NSEG + seg)*NHEADS + hd)*4 + ck)*512;

  if (kbase + qt*64*R >= SEQ || kbase + cofs*R >= SEQ) {
    size_t ob2 = obase + qt*64;
    int row = tid>>2, cb = (tid&3)*16;
    *(bs8*)(&OB[(ob2 + row)*64 + cb])     = z;
    *(bs8*)(&OB[(ob2 + row)*64 + cb + 8]) = z;
    if (tid < 64) LB[ob2 + tid] = NEGV;
    return;
  }

  const int j0 = qt*64 + w*16;
  const unsigned short* qkvb = qkv + (size_t)b*SEQ*QKVW;

  bs8 qf0 = z, qf1 = z;
  {
    int qpos = kbase + (j0 + l16)*R;
    if (qpos < SEQ) {
      const unsigned short* qrow = qkvb + (size_t)qpos*QKVW + hd*64 + g*8;
      qf0 = *(const bs8*)(qrow);
      qf1 = *(const bs8*)(qrow + 32);
    }
  }

  const int dbK = tid&7, kkKb = tid>>3;
  const int kkV = tid&127, dbV0 = tid>>7;
  const unsigned short* pK = qkvb + (size_t)(kbase + (cofs + kkKb)*R)*QKVW + EMB + hd*64 + dbK*8;
  const unsigned short* pV = qkvb + (size_t)(kbase + (cofs + kkV)*R)*QKVW + 1536 + hd*64 + dbV0*8;
  const size_t stepIt = (size_t)32*R*QKVW;
  const bool fullc = (kbase + (cofs + 127)*R) < SEQ;
  bs8 kreg[4], vreg[4];
  if (fullc) {
#pragma unroll
    for (int it=0; it<4; ++it) kreg[it] = *(const bs8*)(pK + (size_t)it*stepIt);
#pragma unroll
    for (int it=0; it<4; ++it) vreg[it] = *(const bs8*)(pV + it*16);
  } else {
#pragma unroll
    for (int it=0; it<4; ++it)
      kreg[it] = (kbase + (cofs + kkKb + it*32)*R < SEQ)
                 ? *(const bs8*)(pK + (size_t)it*stepIt) : z;
    const bool vv = (kbase + (cofs + kkV)*R) < SEQ;
#pragma unroll
    for (int it=0; it<4; ++it) vreg[it] = vv ? *(const bs8*)(pV + it*16) : z;
  }
#pragma unroll
  for (int it=0; it<4; ++it) {
    *(bs8*)(lK + (kkKb + it*32)*72 + dbK*8) = kreg[it];
#pragma unroll
    for (int ii=0; ii<8; ++ii) lVt[((dbV0+it*2)*8+ii)*136 + kkV] = (unsigned short)vreg[it][ii];
  }
  __syncthreads();

  f4 sc[8];
  __builtin_amdgcn_s_setprio(1);
#pragma unroll
  for (int kt=0; kt<8; ++kt) {
    int key = kt*16 + l16;
    bs8 kf0 = *(const bs8*)(lK + key*72 + g*8);
    bs8 kf1 = *(const bs8*)(lK + key*72 + 32 + g*8);
    f4 acc = {0.f,0.f,0.f,0.f};
    acc = __builtin_amdgcn_mfma_f32_16x16x32_bf16(qf0, kf0, acc, 0,0,0);
    acc = __builtin_amdgcn_mfma_f32_16x16x32_bf16(qf1, kf1, acc, 0,0,0);
    sc[kt] = acc;
  }
  __builtin_amdgcn_s_setprio(0);
  __syncthreads();

  if (!fullc) {
#pragma unroll
    for (int kt=0; kt<8; ++kt) {
      bool kvld = (kbase + (cofs + kt*16 + l16)*R) < SEQ;
#pragma unroll
      for (int r=0;r<4;++r) sc[kt][r] = kvld ? sc[kt][r] : NEGV;
    }
  }
  float rm[4], rs[4];
#pragma unroll
  for (int r=0;r<4;++r) {
    float mx = sc[0][r];
#pragma unroll
    for (int kt=1;kt<8;++kt) mx = fmaxf(mx, sc[kt][r]);
    mx = fmaxf(mx, __shfl_xor(mx, 1));
    mx = fmaxf(mx, __shfl_xor(mx, 2));
    mx = fmaxf(mx, __shfl_xor(mx, 4));
    mx = fmaxf(mx, __shfl_xor(mx, 8));
    rm[r] = mx*0.125f;
  }
#pragma unroll
  for (int r=0;r<4;++r) {
    float sm = 0.f;
    float nrm = -rm[r];
#pragma unroll
    for (int kt=0;kt<8;++kt) {
      float p = __expf(__builtin_fmaf(sc[kt][r], 0.125f, nrm));
      sc[kt][r] = p; sm += p;
    }
    rs[r] = sm;
  }
  unsigned short* Plw = lK + w*16*136;
#pragma unroll
  for (int kt=0;kt<8;++kt)
#pragma unroll
    for (int r=0;r<4;++r) {
      int row = g*4+r;
      int gr = (kt*2 + (l16>>3)) ^ ((row>>3)&1);
      Plw[row*136 + gr*8 + (l16&7)] = f2bf_fast(sc[kt][r]);
    }
  f4 oacc[4] = {};
  __builtin_amdgcn_s_setprio(1);
#pragma unroll
  for (int ks=0; ks<4; ++ks) {
    int grp = ((ks*4+g) ^ ((l16>>3)&1))*8;
    bs8 pa = *(const bs8*)(Plw + l16*136 + grp);
#pragma unroll
    for (int dt=0; dt<4; ++dt) {
      bs8 vb = *(const bs8*)(lVt + (dt*16+l16)*136 + ks*32 + g*8);
      oacc[dt] = __builtin_amdgcn_mfma_f32_16x16x32_bf16(pa, vb, oacc[dt], 0,0,0);
    }
  }
  __builtin_amdgcn_s_setprio(0);

#pragma unroll
  for (int r=0;r<4;++r) {
    float s = rs[r];
    s += __shfl_xor(s, 1); s += __shfl_xor(s, 2);
    s += __shfl_xor(s, 4); s += __shfl_xor(s, 8);
    rs[r] = s;
  }

#pragma unroll
  for (int dt=0; dt<4; ++dt)
#pragma unroll
    for (int r=0;r<4;++r) {
      int j = j0 + g*4 + r;
      OB[(obase + j)*64 + dt*16 + l16] = f2bf(oacc[dt][r] / rs[r]);
    }
  if (l16 == 0) {
#pragma unroll
    for (int r=0;r<4;++r) LB[obase + j0 + g*4 + r] = rm[r] + __logf(rs[r]);
  }
}

// ---------------- combine 12 partials (4 chunks x 3 branches) via lse softmax
__global__ __launch_bounds__(256) void attn_combine_k(
   const unsigned short* __restrict__ o1, const float* __restrict__ l1,
   const unsigned short* __restrict__ o2, const float* __restrict__ l2,
   const unsigned short* __restrict__ o3, const float* __restrict__ l3,
   unsigned short* __restrict__ attn)
{
  int row = blockIdx.x; int t = threadIdx.x;
  unsigned short* arow = attn + (size_t)row*EMB;
  if (row >= MROWS) { arow[t]=0; arow[t+256]=0; arow[t+512]=0; return; }
  int b = row / SEQ, pos = row - (row/SEQ)*SEQ;
#pragma unroll
  for (int c0=0; c0<3; ++c0) {
    int cc = t + c0*256;
    int hd = cc >> 6, d = cc & 63;
    float La[12], Oa[12];
    {
      int seg = pos >> 9; int j = pos & 511;
      size_t base0 = (((size_t)(b*5 + seg)*NHEADS + hd)*4)*512 + j;
#pragma unroll
      for (int ck=0;ck<4;++ck) {
        La[ck] = l1[base0 + ck*512];
        Oa[ck] = bf2f(o1[(base0 + ck*512)*64 + d]);
      }
    }
    if ((pos & 1) == (hd & 1)) {
      int seg = pos >> 10; int j = ((pos & 1023) - (hd&1)) >> 1;
      size_t base0 = (((size_t)(b*3 + seg)*NHEADS + hd)*4)*512 + j;
#pragma unroll
      for (int ck=0;ck<4;++ck) {
        La[4+ck] = l2[base0 + ck*512];
        Oa[4+ck] = bf2f(o2[(base0 + ck*512)*64 + d]);
      }
    } else {
#pragma unroll
      for (int ck=0;ck<4;++ck) { La[4+ck] = NEGV; Oa[4+ck] = 0.f; }
    }
    if ((pos & 3) == (hd & 3)) {
      int seg = pos >> 11; int j = ((pos & 2047) - (hd&3)) >> 2;
      size_t base0 = (((size_t)(b*2 + seg)*NHEADS + hd)*4)*512 + j;
#pragma unroll
      for (int ck=0;ck<4;++ck) {
        La[8+ck] = l3[base0 + ck*512];
        Oa[8+ck] = bf2f(o3[(base0 + ck*512)*64 + d]);
      }
    } else {
#pragma unroll
      for (int ck=0;ck<4;++ck) { La[8+ck] = NEGV; Oa[8+ck] = 0.f; }
    }
    float M = La[0];
#pragma unroll
    for (int i=1;i<12;++i) M = fmaxf(M, La[i]);
    float acc = 0.f, wsum = 0.f;
#pragma unroll
    for (int i=0;i<12;++i) {
      float e = __expf(La[i] - M);
      acc += e * Oa[i]; wsum += e;
    }
    arow[cc] = f2bf(acc / wsum);
  }
}

extern "C" void kernel_launch(void* const* d_in, const int* in_sizes, int n_in,
                              void* d_out, int out_size, void* d_ws, size_t ws_size,
                              hipStream_t stream) {
  const float* x       = (const float*)d_in[0];
  const float* conv_w  = (const float*)d_in[1];
  const float* conv_b  = (const float*)d_in[2];
  const float* cls     = (const float*)d_in[3];
  const float* pos_e   = (const float*)d_in[4];
  const float* ln1_g   = (const float*)d_in[5];
  const float* ln1_b   = (const float*)d_in[6];
  const float* wq      = (const float*)d_in[7];
  const float* bq      = (const float*)d_in[8];
  const float* wk      = (const float*)d_in[9];
  const float* bk      = (const float*)d_in[10];
  const float* wv      = (const float*)d_in[11];
  const float* bv      = (const float*)d_in[12];
  const float* wo      = (const float*)d_in[13];
  const float* bo      = (const float*)d_in[14];
  const float* ln2_g   = (const float*)d_in[15];
  const float* ln2_b   = (const float*)d_in[16];
  const float* w1      = (const float*)d_in[17];
  const float* b1      = (const float*)d_in[18];
  const float* w2      = (const float*)d_in[19];
  const float* b2      = (const float*)d_in[20];
  const float* nf_g    = (const float*)d_in[21];
  const float* nf_b    = (const float*)d_in[22];

  char* ws = (char*)d_ws;
  size_t off = 0;
  auto alloc = [&](size_t bytes)->char* {
    char* p = ws + off; off += (bytes + 255) & ~(size_t)255; return p;
  };
  unsigned short* wqkv_t = (unsigned short*)alloc((size_t)12*2304*768*2);
  unsigned short* wo_t   = (unsigned short*)alloc((size_t)12*768*768*2);
  unsigned short* w1_t   = (unsigned short*)alloc((size_t)12*3072*768*2);
  unsigned short* w2_t   = (unsigned short*)alloc((size_t)12*768*3072*2);
  unsigned short* cw_b   = (unsigned short*)alloc((size_t)768*4096*2);
  float* bqkv            = (float*)alloc((size_t)12*2304*4);
  unsigned short* Xp     = (unsigned short*)alloc((size_t)4096*4096*2);
  float* H               = (float*)alloc((size_t)MPAD*768*4);
  float* P               = (float*)alloc((size_t)4*MPAD*768*4);
  unsigned short* Y      = (unsigned short*)alloc((size_t)MPAD*768*2);
  unsigned short* QKV    = (unsigned short*)alloc((size_t)MPAD*2304*2);
  unsigned short* ATT    = (unsigned short*)alloc((size_t)MPAD*768*2);
  unsigned short* Y2     = (unsigned short*)alloc((size_t)MPAD*3072*2);
  unsigned short* O1 = (unsigned short*)alloc((size_t)2*5*12*4*512*64*2);
  unsigned short* O2 = (unsigned short*)alloc((size_t)2*3*12*4*512*64*2);
  unsigned short* O3 = (unsigned short*)alloc((size_t)2*2*12*4*512*64*2);
  float* L1 = (float*)alloc((size_t)2*5*12*4*512*4);
  float* L2 = (float*)alloc((size_t)2*3*12*4*512*4);
  float* L3 = (float*)alloc((size_t)2*2*12*4*512*4);
  const size_t PSTR = (size_t)MPAD*768;

  dim3 tb(32,8);
  wtr_k<<<dim3(24,24,12), tb, 0, stream>>>(wq, wqkv_t, 768, 768, 2304, 0);
  wtr_k<<<dim3(24,24,12), tb, 0, stream>>>(wk, wqkv_t, 768, 768, 2304, 768);
  wtr_k<<<dim3(24,24,12), tb, 0, stream>>>(wv, wqkv_t, 768, 768, 2304, 1536);
  wtr_k<<<dim3(24,24,12), tb, 0, stream>>>(wo, wo_t, 768, 768, 768, 0);
  wtr_k<<<dim3(24,96,12), tb, 0, stream>>>(w1, w1_t, 768, 3072, 3072, 0);
  wtr_k<<<dim3(96,24,12), tb, 0, stream>>>(w2, w2_t, 3072, 768, 768, 0);
  castconv_k<<<3072,256,0,stream>>>(conv_w, cw_b);
  biascat_k<<<108,256,0,stream>>>(bq,bk,bv,bqkv);
  patchify_k<<<16384,256,0,stream>>>(x, Xp);
  gemm_k<3,4><<<dim3(6,32,4),512,0,stream>>>(Xp, cw_b, conv_b, nullptr, P, 4096, 768, PSTR);
  assemble_k<<<MPAD,256,0,stream>>>(P, PSTR, cls, pos_e, H);

  for (int l=0;l<12;++l) {
    if (l==0) ln_k<<<MPAD,256,0,stream>>>(H, ln1_g, ln1_b, Y);
    else ln_red_k<2><<<MPAD,256,0,stream>>>(H, P, PSTR, ln1_g + l*768, ln1_b + l*768, Y);
    gemm_k<0,1><<<dim3(18,33),512,0,stream>>>(Y, wqkv_t + (size_t)l*2304*768, bqkv + l*2304, QKV, nullptr, 768, 2304, 0);
    attn_all_k<<<7680,256,0,stream>>>(QKV, O1,L1,O2,L2,O3,L3);
    attn_combine_k<<<MPAD,256,0,stream>>>(O1,L1,O2,L2,O3,L3, ATT);
    gemm_k<3,2><<<dim3(6,33,2),512,0,stream>>>(ATT, wo_t + (size_t)l*768*768, bo + l*768, nullptr, P, 768, 768, PSTR);
    ln_red_k<2><<<MPAD,256,0,stream>>>(H, P, PSTR, ln2_g + l*768, ln2_b + l*768, Y);
    gemm_k<1,1><<<dim3(24,33),512,0,stream>>>(Y, w1_t + (size_t)l*3072*768, b1 + l*3072, Y2, nullptr, 768, 3072, 0);
    gemm_k<3,2><<<dim3(6,33,2),512,0,stream>>>(Y2, w2_t + (size_t)l*768*3072, b2 + l*768, nullptr, P, 3072, 768, PSTR);
  }
  final_ln_red_k<2><<<2,256,0,stream>>>(H, P, PSTR, nf_g, nf_b, (float*)d_out);
}